// Round 1
// baseline (3131.847 us; speedup 1.0000x reference)
//
#include <hip/hip_runtime.h>
#include <hip/hip_bf16.h>

#define HW 128
#define NPIX (HW * HW)
#define EPS 1e-4f

// ---------------------------------------------------------------------------
// Direct 3x3 conv, NCHW, pad=1. Block = 256 threads = 16x16 pixel tile.
// Each thread computes CO_PT consecutive output channels for one pixel.
// grid = (8, 8, COUT/CO_PT). Weight addresses are block-uniform -> s_load.
// ---------------------------------------------------------------------------
template <int CIN, int CO_PT, bool LEAKY>
__global__ __launch_bounds__(256) void conv3x3_k(
    const float* __restrict__ in, const float* __restrict__ w,
    const float* __restrict__ b, float* __restrict__ out) {
  const int tx = threadIdx.x & 15;
  const int ty = threadIdx.x >> 4;
  const int x = blockIdx.x * 16 + tx;
  const int y = blockIdx.y * 16 + ty;
  const int co0 = blockIdx.z * CO_PT;

  float acc[CO_PT];
#pragma unroll
  for (int i = 0; i < CO_PT; i++) acc[i] = b[co0 + i];

  for (int ci = 0; ci < CIN; ci++) {
    const float* ip = in + ci * NPIX;
    float v[9];
#pragma unroll
    for (int t = 0; t < 9; t++) {
      const int ny = y + t / 3 - 1;
      const int nx = x + t % 3 - 1;
      const bool ok = ((unsigned)ny < (unsigned)HW) && ((unsigned)nx < (unsigned)HW);
      v[t] = ok ? ip[ny * HW + nx] : 0.f;
    }
    const float* wp = w + ((long)co0 * CIN + ci) * 9;
#pragma unroll
    for (int i = 0; i < CO_PT; i++) {
#pragma unroll
      for (int t = 0; t < 9; t++)
        acc[i] = fmaf(wp[i * CIN * 9 + t], v[t], acc[i]);
    }
  }

#pragma unroll
  for (int i = 0; i < CO_PT; i++) {
    float r = acc[i];
    if (LEAKY) r = (r > 0.f) ? r : 0.01f * r;
    out[(co0 + i) * NPIX + y * HW + x] = r;
  }
}

// ---------------------------------------------------------------------------
// Fused softmax + weighted-least-squares + solve + center prediction.
// One thread per pixel. logits layout [441][NPIX].
//   A_hat = sum_k u_k x_k x_k^T (upper triangle), b_hat = sum_k u_k x_k y_k
//   u_k = exp(l_k - max), S = sum u_k (over ALL 441, incl. out-of-bounds)
//   solve (A_hat + S*R) p = b_hat   with R = EPS*I except R[0][0]=0
//   out_c = domain . p[:,c],  domain = design at center pixel.
// Design x = [1, input[3..9]]; y = input[0..2]; zero-padded windows.
// ---------------------------------------------------------------------------
__global__ __launch_bounds__(256) void wls_k(
    const float* __restrict__ input, const float* __restrict__ logits,
    float* __restrict__ out) {
  const int p = blockIdx.x * 256 + threadIdx.x;
  const int x = p & (HW - 1);
  const int y = p >> 7;

  // pass 1: max logit
  float m = -1e30f;
  for (int k = 0; k < 441; k++) m = fmaxf(m, logits[k * NPIX + p]);

  // pass 2: accumulate
  float A[36];  // upper triangle, idx(i,j) = i*8 - i*(i-1)/2 + (j-i)
#pragma unroll
  for (int i = 0; i < 36; i++) A[i] = 0.f;
  float Bm[8][3];
#pragma unroll
  for (int i = 0; i < 8; i++)
#pragma unroll
    for (int c = 0; c < 3; c++) Bm[i][c] = 0.f;
  float S = 0.f;

  for (int ky = 0; ky < 21; ky++) {
    const int ny = y + ky - 10;
    const bool rowok = (unsigned)ny < (unsigned)HW;
    for (int kx = 0; kx < 21; kx++) {
      const int k = ky * 21 + kx;
      const float u = __expf(logits[k * NPIX + p] - m);
      S += u;
      const int nx = x + kx - 10;
      if (!rowok || (unsigned)nx >= (unsigned)HW) continue;
      const int q = ny * HW + nx;
      float xv[8];
      xv[0] = 1.f;
#pragma unroll
      for (int i = 1; i < 8; i++) xv[i] = input[(2 + i) * NPIX + q];
      float yv[3];
#pragma unroll
      for (int c = 0; c < 3; c++) yv[c] = input[c * NPIX + q];
      float ux[8];
#pragma unroll
      for (int i = 0; i < 8; i++) ux[i] = u * xv[i];
      // A[0][j] += u * xv[j] = ux[j]
#pragma unroll
      for (int j = 0; j < 8; j++) A[j] += ux[j];
#pragma unroll
      for (int i = 1; i < 8; i++) {
#pragma unroll
        for (int j = i; j < 8; j++)
          A[i * 8 - i * (i - 1) / 2 + (j - i)] =
              fmaf(ux[i], xv[j], A[i * 8 - i * (i - 1) / 2 + (j - i)]);
      }
#pragma unroll
      for (int i = 0; i < 8; i++)
#pragma unroll
        for (int c = 0; c < 3; c++) Bm[i][c] = fmaf(ux[i], yv[c], Bm[i][c]);
    }
  }

  // build full matrix + regularization (scaled by S)
  float M[8][8];
#pragma unroll
  for (int i = 0; i < 8; i++)
#pragma unroll
    for (int j = 0; j < 8; j++) {
      const int lo = (i < j) ? i : j;
      const int hi = (i < j) ? j : i;
      M[i][j] = A[lo * 8 - lo * (lo - 1) / 2 + (hi - lo)];
    }
#pragma unroll
  for (int i = 1; i < 8; i++) M[i][i] += S * EPS;

  // Gaussian elimination (SPD, no pivoting), 3 RHS, fully unrolled
#pragma unroll
  for (int c = 0; c < 8; c++) {
    const float inv = 1.f / M[c][c];
#pragma unroll
    for (int r = c + 1; r < 8; r++) {
      const float f = M[r][c] * inv;
#pragma unroll
      for (int j = c + 1; j < 8; j++) M[r][j] = fmaf(-f, M[c][j], M[r][j]);
#pragma unroll
      for (int cc = 0; cc < 3; cc++) Bm[r][cc] = fmaf(-f, Bm[c][cc], Bm[r][cc]);
    }
  }
  float para[8][3];
#pragma unroll
  for (int r = 7; r >= 0; r--) {
#pragma unroll
    for (int cc = 0; cc < 3; cc++) {
      float s = Bm[r][cc];
#pragma unroll
      for (int j = r + 1; j < 8; j++) s = fmaf(-M[r][j], para[j][cc], s);
      para[r][cc] = s / M[r][r];
    }
  }

  // center prediction: domain = [1, input[3..9] at p]
  float dv[8];
  dv[0] = 1.f;
#pragma unroll
  for (int i = 1; i < 8; i++) dv[i] = input[(2 + i) * NPIX + p];
#pragma unroll
  for (int c = 0; c < 3; c++) {
    float s = 0.f;
#pragma unroll
    for (int i = 0; i < 8; i++) s = fmaf(dv[i], para[i][c], s);
    out[c * NPIX + p] = s;
  }
}

extern "C" void kernel_launch(void* const* d_in, const int* in_sizes, int n_in,
                              void* d_out, int out_size, void* d_ws, size_t ws_size,
                              hipStream_t stream) {
  const float* input = (const float*)d_in[0];
  // d_in[1] = ref (unused by the computed path)
  const float* w0 = (const float*)d_in[2];
  const float* b0 = (const float*)d_in[3];
  const float* wmid = (const float*)d_in[4];
  const float* bmid = (const float*)d_in[5];
  const float* wfin = (const float*)d_in[6];
  const float* bfin = (const float*)d_in[7];
  float* out = (float*)d_out;

  float* buf0 = (float*)d_ws;                 // 100*NPIX
  float* buf1 = buf0 + 100 * NPIX;            // 100*NPIX
  float* logits = buf1 + 100 * NPIX;          // 441*NPIX

  dim3 blk(256);
  // conv0: 10 -> 100, no activation
  conv3x3_k<10, 10, false><<<dim3(8, 8, 10), blk, 0, stream>>>(input, w0, b0, buf0);
  // 23 mid convs with leaky relu, ping-pong
  for (int t = 0; t < 23; t++) {
    const float* src = (t & 1) ? buf1 : buf0;
    float* dst = (t & 1) ? buf0 : buf1;
    conv3x3_k<100, 10, true><<<dim3(8, 8, 10), blk, 0, stream>>>(
        src, wmid + (long)t * 100 * 100 * 9, bmid + t * 100, dst);
  }
  // final: 100 -> 441 logits (t=22 even wrote buf1)
  conv3x3_k<100, 21, false><<<dim3(8, 8, 21), blk, 0, stream>>>(buf1, wfin, bfin, logits);
  // fused softmax + WLS + solve + output
  wls_k<<<dim3(NPIX / 256), blk, 0, stream>>>(input, logits, out);
}

// Round 3
// 1101.316 us; speedup vs baseline: 2.8437x; 2.8437x over previous
//
#include <hip/hip_runtime.h>
#include <hip/hip_bf16.h>

#define HW 128
#define NPIX (HW * HW)
#define HB 130            // halo-padded activation image width
#define HPIX (HB * HB)
#define ITW 148           // halo-padded transposed-input width (halo 10)
#define EPS 1e-4f

typedef __attribute__((ext_vector_type(4))) float f32x4;
typedef _Float16 f16;
typedef __attribute__((ext_vector_type(8))) _Float16 f16x8;
typedef __attribute__((ext_vector_type(4))) _Float16 f16x4;
typedef __attribute__((ext_vector_type(4))) int i32x4;

// ---------------------------------------------------------------------------
// zero an int4 buffer
// ---------------------------------------------------------------------------
__global__ __launch_bounds__(256) void zero_buf(i32x4* __restrict__ p, int n) {
  int i = blockIdx.x * 256 + threadIdx.x;
  if (i < n) p[i] = i32x4{0, 0, 0, 0};
}

// ---------------------------------------------------------------------------
// transpose input NCHW fp32 -> halo-padded [148*148][16] fp32
// ch0 = validity/ones, ch1..3 = input[0..2], ch4..10 = input[3..9], rest 0
// ---------------------------------------------------------------------------
__global__ __launch_bounds__(256) void prep_input_k(
    const float* __restrict__ in, float* __restrict__ itp) {
  int idx = blockIdx.x * 256 + threadIdx.x;
  if (idx >= ITW * ITW) return;
  int py = idx / ITW, px = idx - py * ITW;
  float v[16];
#pragma unroll
  for (int i = 0; i < 16; i++) v[i] = 0.f;
  if (py >= 10 && py < 138 && px >= 10 && px < 138) {
    int p = (py - 10) * HW + (px - 10);
    v[0] = 1.f;
#pragma unroll
    for (int c = 0; c < 10; c++) v[1 + c] = in[c * NPIX + p];
  }
  float4* op = (float4*)(itp + idx * 16);
#pragma unroll
  for (int g = 0; g < 4; g++)
    op[g] = make_float4(v[g * 4], v[g * 4 + 1], v[g * 4 + 2], v[g * 4 + 3]);
}

// ---------------------------------------------------------------------------
// weight repack: wmid [23][100][100][3][3] f32 -> [23][9][128][128] f16
// ---------------------------------------------------------------------------
__global__ __launch_bounds__(256) void pack_wmid_k(
    const float* __restrict__ wm, f16* __restrict__ wb) {
  int idx = blockIdx.x * 256 + threadIdx.x;  // 23*9*128*128 total
  int L = idx / (9 * 16384);
  int r = idx - L * (9 * 16384);
  int t = r >> 14;
  int q = r & 16383;
  int co = q >> 7, ci = q & 127;
  float v = 0.f;
  if (co < 100 && ci < 100) v = wm[((L * 100 + co) * 100 + ci) * 9 + t];
  wb[idx] = (f16)v;
}

// wfin [441][100][3][3] f32 -> [9][448][128] f16
__global__ __launch_bounds__(256) void pack_wfin_k(
    const float* __restrict__ wf, f16* __restrict__ wb) {
  int idx = blockIdx.x * 256 + threadIdx.x;  // 9*448*128 total
  int t = idx / (448 * 128);
  int q = idx - t * (448 * 128);
  int co = q >> 7, ci = q & 127;
  float v = 0.f;
  if (co < 441 && ci < 100) v = wf[(co * 100 + ci) * 9 + t];
  wb[idx] = (f16)v;
}

// ---------------------------------------------------------------------------
// conv0: 10 -> 100 direct fp32 (cheap), write f16 halo NHWC [HPIX][128]
// grid (8,8,8), block 256 (16x16 pixel tile), 16 out-ch per thread
// ---------------------------------------------------------------------------
__global__ __launch_bounds__(256) void conv0_k(
    const float* __restrict__ in, const float* __restrict__ w0,
    const float* __restrict__ b0, f16* __restrict__ act) {
  const int tx = threadIdx.x & 15, ty = threadIdx.x >> 4;
  const int x = blockIdx.x * 16 + tx, y = blockIdx.y * 16 + ty;
  const int co0 = blockIdx.z * 16;
  const int nco = max(0, min(16, 100 - co0));
  float acc[16];
#pragma unroll
  for (int i = 0; i < 16; i++) acc[i] = (i < nco) ? b0[co0 + i] : 0.f;
  for (int ci = 0; ci < 10; ci++) {
    const float* ip = in + ci * NPIX;
    float v[9];
#pragma unroll
    for (int t = 0; t < 9; t++) {
      int ny = y + t / 3 - 1, nx = x + t % 3 - 1;
      bool ok = ((unsigned)ny < (unsigned)HW) && ((unsigned)nx < (unsigned)HW);
      v[t] = ok ? ip[ny * HW + nx] : 0.f;
    }
    const float* wp = w0 + (co0 * 10 + ci) * 9;
#pragma unroll
    for (int i = 0; i < 16; i++) {
      if (i < nco) {
#pragma unroll
        for (int t = 0; t < 9; t++)
          acc[i] = fmaf(wp[i * 90 + t], v[t], acc[i]);
      }
    }
  }
  f16* op = act + ((y + 1) * HB + (x + 1)) * 128 + co0;
#pragma unroll
  for (int g = 0; g < 4; g++) {
    f16x4 sv;
#pragma unroll
    for (int j = 0; j < 4; j++) sv[j] = (f16)acc[g * 4 + j];
    *(f16x4*)(op + g * 4) = sv;
  }
}

// ---------------------------------------------------------------------------
// implicit-GEMM 3x3 conv via MFMA f16 (fp32 accum).
// act: [HPIX][128] f16 (halo + pad-ch zeros). wb: [9][COPAD][128] f16.
// Block: 4 waves, tile 64co x 64px (one row segment). Wave: 32co x 32px.
// grid = (256, COPAD/64)
// ---------------------------------------------------------------------------
template <int COPAD, bool FINAL>
__global__ __launch_bounds__(256) void conv_mfma_k(
    const f16* __restrict__ act, const f16* __restrict__ wb,
    const float* __restrict__ bias, int nbias, f16* __restrict__ out) {
  const int l = threadIdx.x & 63;
  const int w = threadIdx.x >> 6;
  const int y = blockIdx.x >> 1;
  const int x0 = (blockIdx.x & 1) * 64;
  const int co_w = blockIdx.y * 64 + (w >> 1) * 32;
  const int px_w = x0 + (w & 1) * 32;
  const int lr = l & 15;
  const int lk = (l >> 4) * 8;

  const f16* ap0 = wb + (co_w + lr) * 128 + lk;
  const int hpA = (y + 1) * HB + (px_w + lr + 1);

  f32x4 acc[2][2];
#pragma unroll
  for (int m = 0; m < 2; m++)
#pragma unroll
    for (int n = 0; n < 2; n++) acc[m][n] = f32x4{0.f, 0.f, 0.f, 0.f};

#pragma unroll
  for (int t = 0; t < 9; t++) {
    const int off = (t / 3 - 1) * HB + (t % 3 - 1);
    const f16* at = ap0 + t * (COPAD * 128);
    const f16* bt = act + (hpA + off) * 128 + lk;
#pragma unroll
    for (int kc = 0; kc < 4; kc++) {
      f16x8 fa0 = *(const f16x8*)(at + kc * 32);
      f16x8 fa1 = *(const f16x8*)(at + 16 * 128 + kc * 32);
      f16x8 fb0 = *(const f16x8*)(bt + kc * 32);
      f16x8 fb1 = *(const f16x8*)(bt + 16 * 128 + kc * 32);
      acc[0][0] = __builtin_amdgcn_mfma_f32_16x16x32_f16(fa0, fb0, acc[0][0], 0, 0, 0);
      acc[1][0] = __builtin_amdgcn_mfma_f32_16x16x32_f16(fa1, fb0, acc[1][0], 0, 0, 0);
      acc[0][1] = __builtin_amdgcn_mfma_f32_16x16x32_f16(fa0, fb1, acc[0][1], 0, 0, 0);
      acc[1][1] = __builtin_amdgcn_mfma_f32_16x16x32_f16(fa1, fb1, acc[1][1], 0, 0, 0);
    }
  }

#pragma unroll
  for (int mm = 0; mm < 2; mm++) {
#pragma unroll
    for (int nn = 0; nn < 2; nn++) {
      int co = co_w + mm * 16 + (l >> 4) * 4;
      int px = px_w + nn * 16 + lr;
      f16x4 sv;
#pragma unroll
      for (int j = 0; j < 4; j++) {
        float bv = (co + j < nbias) ? bias[co + j] : 0.f;
        float v = acc[mm][nn][j] + bv;
        if (!FINAL) v = v > 0.f ? v : 0.01f * v;
        sv[j] = (f16)v;
      }
      f16* op = FINAL ? out + (y * HW + px) * 448 + co
                      : out + ((y + 1) * HB + (px + 1)) * 128 + co;
      *(f16x4*)op = sv;
    }
  }
}

// ---------------------------------------------------------------------------
// fused softmax + WLS + solve. 4 threads per pixel (window split over parts),
// shuffle-reduce. inputT: [ITW*ITW][16] f32 halo (ch0=valid). logits: [NPIX][448] f16.
// ---------------------------------------------------------------------------
__global__ __launch_bounds__(256) void wls_k(
    const float* __restrict__ itp, const f16* __restrict__ logits,
    float* __restrict__ out) {
  const int tid = threadIdx.x;
  const int part = tid & 3;
  const int p = blockIdx.x * 64 + (tid >> 2);
  const int x = p & (HW - 1), y = p >> 7;
  const int hpc = (y + 10) * ITW + (x + 10);
  const f16* lp = logits + p * 448;
  const int k0 = part * 110;
  const int k1 = (part == 3) ? 441 : k0 + 110;

  float m = -1e30f;
  for (int k = k0; k < k1; k++) m = fmaxf(m, (float)lp[k]);
  m = fmaxf(m, __shfl_xor(m, 1));
  m = fmaxf(m, __shfl_xor(m, 2));

  float A[36];
#pragma unroll
  for (int i = 0; i < 36; i++) A[i] = 0.f;
  float Bm[24];
#pragma unroll
  for (int i = 0; i < 24; i++) Bm[i] = 0.f;
  float S = 0.f;

  for (int k = k0; k < k1; k++) {
    int ky = k / 21, kx = k - ky * 21;
    const float4* q = (const float4*)(itp + (hpc + (ky - 10) * ITW + (kx - 10)) * 16);
    float4 f0 = q[0], f1 = q[1], f2 = q[2];
    float u = __expf((float)lp[k] - m);
    S += u;
    float xv[8] = {f0.x, f1.x, f1.y, f1.z, f1.w, f2.x, f2.y, f2.z};
    float yv[3] = {f0.y, f0.z, f0.w};
    float ux[8];
#pragma unroll
    for (int i = 0; i < 8; i++) ux[i] = u * xv[i];
#pragma unroll
    for (int i = 0; i < 8; i++)
#pragma unroll
      for (int j = i; j < 8; j++) {
        const int idx = i * 8 - i * (i - 1) / 2 + (j - i);
        A[idx] = fmaf(ux[i], xv[j], A[idx]);
      }
#pragma unroll
    for (int i = 0; i < 8; i++)
#pragma unroll
      for (int c = 0; c < 3; c++) Bm[i * 3 + c] = fmaf(ux[i], yv[c], Bm[i * 3 + c]);
  }

  // cross-part reduction (4 lanes per pixel)
#pragma unroll
  for (int i = 0; i < 36; i++) {
    A[i] += __shfl_xor(A[i], 1);
    A[i] += __shfl_xor(A[i], 2);
  }
#pragma unroll
  for (int i = 0; i < 24; i++) {
    Bm[i] += __shfl_xor(Bm[i], 1);
    Bm[i] += __shfl_xor(Bm[i], 2);
  }
  S += __shfl_xor(S, 1);
  S += __shfl_xor(S, 2);

  float M[8][8];
#pragma unroll
  for (int i = 0; i < 8; i++)
#pragma unroll
    for (int j = 0; j < 8; j++) {
      const int lo = (i < j) ? i : j;
      const int hi = (i < j) ? j : i;
      M[i][j] = A[lo * 8 - lo * (lo - 1) / 2 + (hi - lo)];
    }
#pragma unroll
  for (int i = 1; i < 8; i++) M[i][i] += S * EPS;

  float R[8][3];
#pragma unroll
  for (int i = 0; i < 8; i++)
#pragma unroll
    for (int c = 0; c < 3; c++) R[i][c] = Bm[i * 3 + c];

#pragma unroll
  for (int c = 0; c < 8; c++) {
    const float inv = 1.f / M[c][c];
#pragma unroll
    for (int r = c + 1; r < 8; r++) {
      const float f = M[r][c] * inv;
#pragma unroll
      for (int j = c + 1; j < 8; j++) M[r][j] = fmaf(-f, M[c][j], M[r][j]);
#pragma unroll
      for (int cc = 0; cc < 3; cc++) R[r][cc] = fmaf(-f, R[c][cc], R[r][cc]);
    }
  }
  float para[8][3];
#pragma unroll
  for (int r = 7; r >= 0; r--) {
#pragma unroll
    for (int cc = 0; cc < 3; cc++) {
      float s = R[r][cc];
#pragma unroll
      for (int j = r + 1; j < 8; j++) s = fmaf(-M[r][j], para[j][cc], s);
      para[r][cc] = s / M[r][r];
    }
  }

  const float4* qc = (const float4*)(itp + hpc * 16);
  float4 c1 = qc[1], c2 = qc[2];
  float dv[8] = {1.f, c1.x, c1.y, c1.z, c1.w, c2.x, c2.y, c2.z};
  float res = 0.f;
  if (part < 3) {
#pragma unroll
    for (int i = 0; i < 8; i++) res = fmaf(dv[i], para[i][part], res);
    out[part * NPIX + p] = res;
  }
}

// ---------------------------------------------------------------------------
extern "C" void kernel_launch(void* const* d_in, const int* in_sizes, int n_in,
                              void* d_out, int out_size, void* d_ws, size_t ws_size,
                              hipStream_t stream) {
  const float* input = (const float*)d_in[0];
  const float* w0 = (const float*)d_in[2];
  const float* b0 = (const float*)d_in[3];
  const float* wmid = (const float*)d_in[4];
  const float* bmid = (const float*)d_in[5];
  const float* wfin = (const float*)d_in[6];
  const float* bfin = (const float*)d_in[7];
  float* out = (float*)d_out;

  f16* act0 = (f16*)d_ws;                           // 16900*128
  f16* act1 = act0 + HPIX * 128;                    // 16900*128
  f16* logits = act1 + HPIX * 128;                  // 16384*448
  f16* wbuf = logits + NPIX * 448;                  // 23*9*128*128
  f16* wfbuf = wbuf + 23 * 9 * 128 * 128;           // 9*448*128
  float* inputT = (float*)(wfbuf + 9 * 448 * 128);  // 148*148*16

  // zero both act buffers (halo + pad channels); they are contiguous
  {
    int n = (2 * HPIX * 128 * 2) / 16;  // int4 count
    zero_buf<<<(n + 255) / 256, 256, 0, stream>>>((i32x4*)act0, n);
  }
  prep_input_k<<<(ITW * ITW + 255) / 256, 256, 0, stream>>>(input, inputT);
  pack_wmid_k<<<(23 * 9 * 16384) / 256, 256, 0, stream>>>(wmid, wbuf);
  pack_wfin_k<<<(9 * 448 * 128) / 256, 256, 0, stream>>>(wfin, wfbuf);

  conv0_k<<<dim3(8, 8, 8), 256, 0, stream>>>(input, w0, b0, act0);

  for (int L = 0; L < 23; L++) {
    const f16* src = (L & 1) ? act1 : act0;
    f16* dst = (L & 1) ? act0 : act1;
    conv_mfma_k<128, false><<<dim3(256, 2), 256, 0, stream>>>(
        src, wbuf + (long)L * 9 * 128 * 128, bmid + L * 100, 100, dst);
  }
  // 23 layers end in act1
  conv_mfma_k<448, true><<<dim3(256, 7), 256, 0, stream>>>(
      act1, wfbuf, bfin, 441, logits);

  wls_k<<<NPIX * 4 / 256, 256, 0, stream>>>(inputT, logits, out);
}

// Round 4
// 740.991 us; speedup vs baseline: 4.2266x; 1.4863x over previous
//
#include <hip/hip_runtime.h>
#include <hip/hip_bf16.h>

#define HW 128
#define NPIX (HW * HW)
#define HB 130            // halo-padded activation image width
#define HPIX (HB * HB)
#define ITW 148           // halo-padded transposed-input width (halo 10)
#define EPS 1e-4f

typedef __attribute__((ext_vector_type(4))) float f32x4;
typedef _Float16 f16;
typedef __attribute__((ext_vector_type(8))) _Float16 f16x8;
typedef __attribute__((ext_vector_type(4))) _Float16 f16x4;
typedef __attribute__((ext_vector_type(4))) int i32x4;

// ---------------------------------------------------------------------------
__global__ __launch_bounds__(256) void zero_buf(i32x4* __restrict__ p, int n) {
  int i = blockIdx.x * 256 + threadIdx.x;
  if (i < n) p[i] = i32x4{0, 0, 0, 0};
}

// ---------------------------------------------------------------------------
// transpose input NCHW fp32 -> halo-padded [148*148][16] fp32
// ch0 = validity/ones, ch1..3 = input[0..2], ch4..10 = input[3..9], rest 0
// ---------------------------------------------------------------------------
__global__ __launch_bounds__(256) void prep_input_k(
    const float* __restrict__ in, float* __restrict__ itp) {
  int idx = blockIdx.x * 256 + threadIdx.x;
  if (idx >= ITW * ITW) return;
  int py = idx / ITW, px = idx - py * ITW;
  float v[16];
#pragma unroll
  for (int i = 0; i < 16; i++) v[i] = 0.f;
  if (py >= 10 && py < 138 && px >= 10 && px < 138) {
    int p = (py - 10) * HW + (px - 10);
    v[0] = 1.f;
#pragma unroll
    for (int c = 0; c < 10; c++) v[1 + c] = in[c * NPIX + p];
  }
  float4* op = (float4*)(itp + idx * 16);
#pragma unroll
  for (int g = 0; g < 4; g++)
    op[g] = make_float4(v[g * 4], v[g * 4 + 1], v[g * 4 + 2], v[g * 4 + 3]);
}

// ---------------------------------------------------------------------------
// weight repack to MFMA-fragment-major order:
//   wb[L][t][cf][kc][lane][e]  (f16), co = cf*16 + (lane&15),
//   ci = kc*32 + (lane>>4)*8 + e  -> one wave A-frag load = contiguous 1KB.
// wmid [23][100][100][3][3] f32 -> 23*9*8*4*64*8
// ---------------------------------------------------------------------------
__global__ __launch_bounds__(256) void pack_wmid_k(
    const float* __restrict__ wm, f16* __restrict__ wb) {
  int idx = blockIdx.x * 256 + threadIdx.x;  // 23*9*16384
  int e = idx & 7;
  int l = (idx >> 3) & 63;
  int kc = (idx >> 9) & 3;
  int cf = (idx >> 11) & 7;
  int tL = idx >> 14;
  int L = tL / 9;
  int t = tL - L * 9;
  int co = cf * 16 + (l & 15);
  int ci = kc * 32 + (l >> 4) * 8 + e;
  float v = 0.f;
  if (co < 100 && ci < 100) v = wm[((L * 100 + co) * 100 + ci) * 9 + t];
  wb[idx] = (f16)v;
}

// wfin [441][100][3][3] f32 -> [9][32cf][4kc][64][8]  (co padded to 512)
__global__ __launch_bounds__(256) void pack_wfin_k(
    const float* __restrict__ wf, f16* __restrict__ wb) {
  int idx = blockIdx.x * 256 + threadIdx.x;  // 9*65536
  int e = idx & 7;
  int l = (idx >> 3) & 63;
  int kc = (idx >> 9) & 3;
  int cf = (idx >> 11) & 31;
  int t = idx >> 16;
  int co = cf * 16 + (l & 15);
  int ci = kc * 32 + (l >> 4) * 8 + e;
  float v = 0.f;
  if (co < 441 && ci < 100) v = wf[(co * 100 + ci) * 9 + t];
  wb[idx] = (f16)v;
}

// ---------------------------------------------------------------------------
// conv0: 10 -> 100 direct fp32, write f16 halo NHWC [HPIX][128]
// ---------------------------------------------------------------------------
__global__ __launch_bounds__(256) void conv0_k(
    const float* __restrict__ in, const float* __restrict__ w0,
    const float* __restrict__ b0, f16* __restrict__ act) {
  const int tx = threadIdx.x & 15, ty = threadIdx.x >> 4;
  const int x = blockIdx.x * 16 + tx, y = blockIdx.y * 16 + ty;
  const int co0 = blockIdx.z * 16;
  const int nco = max(0, min(16, 100 - co0));
  float acc[16];
#pragma unroll
  for (int i = 0; i < 16; i++) acc[i] = (i < nco) ? b0[co0 + i] : 0.f;
  for (int ci = 0; ci < 10; ci++) {
    const float* ip = in + ci * NPIX;
    float v[9];
#pragma unroll
    for (int t = 0; t < 9; t++) {
      int ny = y + t / 3 - 1, nx = x + t % 3 - 1;
      bool ok = ((unsigned)ny < (unsigned)HW) && ((unsigned)nx < (unsigned)HW);
      v[t] = ok ? ip[ny * HW + nx] : 0.f;
    }
    const float* wp = w0 + (co0 * 10 + ci) * 9;
#pragma unroll
    for (int i = 0; i < 16; i++) {
      if (i < nco) {
#pragma unroll
        for (int t = 0; t < 9; t++)
          acc[i] = fmaf(wp[i * 90 + t], v[t], acc[i]);
      }
    }
  }
  f16* op = act + ((y + 1) * HB + (x + 1)) * 128 + co0;
#pragma unroll
  for (int g = 0; g < 4; g++) {
    f16x4 sv;
#pragma unroll
    for (int j = 0; j < 4; j++) sv[j] = (f16)acc[g * 4 + j];
    *(f16x4*)(op + g * 4) = sv;
  }
}

// ---------------------------------------------------------------------------
// implicit-GEMM 3x3 conv, MFMA f16, LDS-staged B with XOR chunk swizzle.
// Block = 256 thr = 4 waves, tile 128co x 64px. Wave = 64co x 32px, acc[4][2].
// grid = (256 [y*2 + xhalf], COPAD/128).
// act: [HPIX][128] f16 linear.  wb: frag-major [9][NCF][4][64][8] f16.
// LDS: 3 rows x 66 px x 16 chunks x 16B, chunk swizzled by (lp&7).
// ---------------------------------------------------------------------------
template <int NCF, bool FINAL>
__global__ __launch_bounds__(256) void conv_mfma_k(
    const f16* __restrict__ act, const f16* __restrict__ wb,
    const float* __restrict__ bias, f16* __restrict__ out) {
  __shared__ f16 ldsB[3 * 66 * 128];
  f16x8* ldsB8 = (f16x8*)ldsB;
  const f16x8* actF8 = (const f16x8*)act;
  const f16x8* wbF8 = (const f16x8*)wb;

  const int tid = threadIdx.x;
  const int l = tid & 63;
  const int w = tid >> 6;
  const int lr = l & 15;
  const int lg = l >> 4;
  const int y = blockIdx.x >> 1;
  const int x0 = (blockIdx.x & 1) * 64;
  const int co_half = w >> 1;
  const int px_half = w & 1;

  // ---- stage B tile: rows y..y+2 (halo coords), px x0..x0+65, swizzled ----
#pragma unroll
  for (int it = 0; it < 13; it++) {
    int cid = it * 256 + tid;
    if (cid < 3168) {
      int row = cid / 1056;          // 66*16
      int rem = cid - row * 1056;
      int lp = rem >> 4;
      int c = rem & 15;
      f16x8 v = actF8[((y + row) * HB + x0 + lp) * 16 + (c ^ (lp & 7))];
      ldsB8[(row * 66 + lp) * 16 + c] = v;
    }
  }
  __syncthreads();

  f32x4 acc[4][2];
#pragma unroll
  for (int m = 0; m < 4; m++)
#pragma unroll
    for (int n = 0; n < 2; n++) acc[m][n] = f32x4{0.f, 0.f, 0.f, 0.f};

  const int cf_base = blockIdx.y * 8 + co_half * 4;
  const int lpb = px_half * 32 + lr;

#pragma unroll
  for (int t = 0; t < 9; t++) {
    const int dx = t % 3, r = t / 3;
    // hoist all 16 A-frags for this tap (coalesced 1KB loads, L2-resident)
    f16x8 af[4][4];  // [kc][m]
#pragma unroll
    for (int kc = 0; kc < 4; kc++)
#pragma unroll
      for (int m = 0; m < 4; m++)
        af[kc][m] = wbF8[((t * NCF + cf_base + m) * 4 + kc) * 64 + l];
#pragma unroll
    for (int kc = 0; kc < 4; kc++) {
      const int kq = kc * 4 + lg;
      f16x8 fb[2];
#pragma unroll
      for (int n = 0; n < 2; n++) {
        const int lp = lpb + n * 16 + dx;
        fb[n] = ldsB8[((r * 66 + lp) << 4) + (kq ^ (lp & 7))];
      }
#pragma unroll
      for (int m = 0; m < 4; m++) {
        acc[m][0] = __builtin_amdgcn_mfma_f32_16x16x32_f16(af[kc][m], fb[0], acc[m][0], 0, 0, 0);
        acc[m][1] = __builtin_amdgcn_mfma_f32_16x16x32_f16(af[kc][m], fb[1], acc[m][1], 0, 0, 0);
      }
    }
  }

  // ---- epilogue ----
#pragma unroll
  for (int m = 0; m < 4; m++) {
#pragma unroll
    for (int n = 0; n < 2; n++) {
      int co = blockIdx.y * 128 + co_half * 64 + m * 16 + lg * 4;
      int px = x0 + px_half * 32 + n * 16 + lr;
      if (FINAL && co >= 448) continue;
      f16x4 sv;
#pragma unroll
      for (int j = 0; j < 4; j++) {
        float bv = (co + j < (FINAL ? 441 : 100)) ? bias[co + j] : 0.f;
        float v = acc[m][n][j] + bv;
        if (!FINAL) v = v > 0.f ? v : 0.01f * v;
        sv[j] = (f16)v;
      }
      f16* op = FINAL ? out + (y * HW + px) * 448 + co
                      : out + ((y + 1) * HB + (px + 1)) * 128 + co;
      *(f16x4*)op = sv;
    }
  }
}

// ---------------------------------------------------------------------------
// fused softmax + WLS + solve. 4 threads per pixel, shuffle-reduce.
// inputT: [ITW*ITW][16] f32 halo (ch0=valid). logits: [NPIX][448] f16.
// ---------------------------------------------------------------------------
__global__ __launch_bounds__(256) void wls_k(
    const float* __restrict__ itp, const f16* __restrict__ logits,
    float* __restrict__ out) {
  const int tid = threadIdx.x;
  const int part = tid & 3;
  const int p = blockIdx.x * 64 + (tid >> 2);
  const int x = p & (HW - 1), y = p >> 7;
  const int hpc = (y + 10) * ITW + (x + 10);
  const f16* lp = logits + p * 448;
  const int k0 = part * 110;
  const int k1 = (part == 3) ? 441 : k0 + 110;

  float m = -1e30f;
  for (int k = k0; k < k1; k++) m = fmaxf(m, (float)lp[k]);
  m = fmaxf(m, __shfl_xor(m, 1));
  m = fmaxf(m, __shfl_xor(m, 2));

  float A[36];
#pragma unroll
  for (int i = 0; i < 36; i++) A[i] = 0.f;
  float Bm[24];
#pragma unroll
  for (int i = 0; i < 24; i++) Bm[i] = 0.f;
  float S = 0.f;

  for (int k = k0; k < k1; k++) {
    int ky = k / 21, kx = k - ky * 21;
    const float4* q = (const float4*)(itp + (hpc + (ky - 10) * ITW + (kx - 10)) * 16);
    float4 f0 = q[0], f1 = q[1], f2 = q[2];
    float u = __expf((float)lp[k] - m);
    S += u;
    float xv[8] = {f0.x, f1.x, f1.y, f1.z, f1.w, f2.x, f2.y, f2.z};
    float yv[3] = {f0.y, f0.z, f0.w};
    float ux[8];
#pragma unroll
    for (int i = 0; i < 8; i++) ux[i] = u * xv[i];
#pragma unroll
    for (int i = 0; i < 8; i++)
#pragma unroll
      for (int j = i; j < 8; j++) {
        const int idx = i * 8 - i * (i - 1) / 2 + (j - i);
        A[idx] = fmaf(ux[i], xv[j], A[idx]);
      }
#pragma unroll
    for (int i = 0; i < 8; i++)
#pragma unroll
      for (int c = 0; c < 3; c++) Bm[i * 3 + c] = fmaf(ux[i], yv[c], Bm[i * 3 + c]);
  }

#pragma unroll
  for (int i = 0; i < 36; i++) {
    A[i] += __shfl_xor(A[i], 1);
    A[i] += __shfl_xor(A[i], 2);
  }
#pragma unroll
  for (int i = 0; i < 24; i++) {
    Bm[i] += __shfl_xor(Bm[i], 1);
    Bm[i] += __shfl_xor(Bm[i], 2);
  }
  S += __shfl_xor(S, 1);
  S += __shfl_xor(S, 2);

  float M[8][8];
#pragma unroll
  for (int i = 0; i < 8; i++)
#pragma unroll
    for (int j = 0; j < 8; j++) {
      const int lo = (i < j) ? i : j;
      const int hi = (i < j) ? j : i;
      M[i][j] = A[lo * 8 - lo * (lo - 1) / 2 + (hi - lo)];
    }
#pragma unroll
  for (int i = 1; i < 8; i++) M[i][i] += S * EPS;

  float R[8][3];
#pragma unroll
  for (int i = 0; i < 8; i++)
#pragma unroll
    for (int c = 0; c < 3; c++) R[i][c] = Bm[i * 3 + c];

#pragma unroll
  for (int c = 0; c < 8; c++) {
    const float inv = 1.f / M[c][c];
#pragma unroll
    for (int r = c + 1; r < 8; r++) {
      const float f = M[r][c] * inv;
#pragma unroll
      for (int j = c + 1; j < 8; j++) M[r][j] = fmaf(-f, M[c][j], M[r][j]);
#pragma unroll
      for (int cc = 0; cc < 3; cc++) R[r][cc] = fmaf(-f, R[c][cc], R[r][cc]);
    }
  }
  float para[8][3];
#pragma unroll
  for (int r = 7; r >= 0; r--) {
#pragma unroll
    for (int cc = 0; cc < 3; cc++) {
      float s = R[r][cc];
#pragma unroll
      for (int j = r + 1; j < 8; j++) s = fmaf(-M[r][j], para[j][cc], s);
      para[r][cc] = s / M[r][r];
    }
  }

  const float4* qc = (const float4*)(itp + hpc * 16);
  float4 c1 = qc[1], c2 = qc[2];
  float dv[8] = {1.f, c1.x, c1.y, c1.z, c1.w, c2.x, c2.y, c2.z};
  float res = 0.f;
  if (part < 3) {
#pragma unroll
    for (int i = 0; i < 8; i++) res = fmaf(dv[i], para[i][part], res);
    out[part * NPIX + p] = res;
  }
}

// ---------------------------------------------------------------------------
extern "C" void kernel_launch(void* const* d_in, const int* in_sizes, int n_in,
                              void* d_out, int out_size, void* d_ws, size_t ws_size,
                              hipStream_t stream) {
  const float* input = (const float*)d_in[0];
  const float* w0 = (const float*)d_in[2];
  const float* b0 = (const float*)d_in[3];
  const float* wmid = (const float*)d_in[4];
  const float* bmid = (const float*)d_in[5];
  const float* wfin = (const float*)d_in[6];
  const float* bfin = (const float*)d_in[7];
  float* out = (float*)d_out;

  f16* act0 = (f16*)d_ws;                           // HPIX*128
  f16* act1 = act0 + HPIX * 128;                    // HPIX*128
  f16* logits = act1 + HPIX * 128;                  // NPIX*448
  f16* wbuf = logits + NPIX * 448;                  // 23*9*16384
  f16* wfbuf = wbuf + 23 * 9 * 16384;               // 9*65536
  float* inputT = (float*)(wfbuf + 9 * 65536);      // 148*148*16

  // zero both act buffers (halo + pad channels)
  {
    int n = (2 * HPIX * 128 * 2) / 16;
    zero_buf<<<(n + 255) / 256, 256, 0, stream>>>((i32x4*)act0, n);
  }
  prep_input_k<<<(ITW * ITW + 255) / 256, 256, 0, stream>>>(input, inputT);
  pack_wmid_k<<<(23 * 9 * 16384) / 256, 256, 0, stream>>>(wmid, wbuf);
  pack_wfin_k<<<(9 * 65536) / 256, 256, 0, stream>>>(wfin, wfbuf);

  conv0_k<<<dim3(8, 8, 8), 256, 0, stream>>>(input, w0, b0, act0);

  for (int L = 0; L < 23; L++) {
    const f16* src = (L & 1) ? act1 : act0;
    f16* dst = (L & 1) ? act0 : act1;
    conv_mfma_k<8, false><<<dim3(256, 1), 256, 0, stream>>>(
        src, wbuf + (long)L * 9 * 16384, bmid + L * 100, dst);
  }
  // 23 layers end in act1
  conv_mfma_k<32, true><<<dim3(256, 4), 256, 0, stream>>>(
      act1, wfbuf, bfin, logits);

  wls_k<<<NPIX * 4 / 256, 256, 0, stream>>>(inputT, logits, out);
}

// Round 5
// 551.770 us; speedup vs baseline: 5.6760x; 1.3429x over previous
//
#include <hip/hip_runtime.h>
#include <hip/hip_bf16.h>

#define HW 128
#define NPIX (HW * HW)
#define HB 130            // halo-padded activation image width
#define HPIX (HB * HB)
#define ITW 148           // halo-padded transposed-input width (halo 10)
#define EPS 1e-4f

typedef __attribute__((ext_vector_type(4))) float f32x4;
typedef _Float16 f16;
typedef __attribute__((ext_vector_type(8))) _Float16 f16x8;
typedef __attribute__((ext_vector_type(4))) _Float16 f16x4;
typedef __attribute__((ext_vector_type(4))) int i32x4;

// async global->LDS, 16B per lane; g is per-lane, l must be wave-uniform base
__device__ __forceinline__ void gload16(const f16* g, f16* l) {
  __builtin_amdgcn_global_load_lds(
      (const __attribute__((address_space(1))) unsigned int*)(const void*)g,
      (__attribute__((address_space(3))) unsigned int*)(void*)l, 16, 0, 0);
}

// ---------------------------------------------------------------------------
__global__ __launch_bounds__(256) void zero_buf(i32x4* __restrict__ p, int n) {
  int i = blockIdx.x * 256 + threadIdx.x;
  if (i < n) p[i] = i32x4{0, 0, 0, 0};
}

// ---------------------------------------------------------------------------
// transpose input NCHW fp32 -> halo-padded [148*148][16] fp32
// ch0 = validity/ones, ch1..3 = input[0..2], ch4..10 = input[3..9], rest 0
// ---------------------------------------------------------------------------
__global__ __launch_bounds__(256) void prep_input_k(
    const float* __restrict__ in, float* __restrict__ itp) {
  int idx = blockIdx.x * 256 + threadIdx.x;
  if (idx >= ITW * ITW) return;
  int py = idx / ITW, px = idx - py * ITW;
  float v[16];
#pragma unroll
  for (int i = 0; i < 16; i++) v[i] = 0.f;
  if (py >= 10 && py < 138 && px >= 10 && px < 138) {
    int p = (py - 10) * HW + (px - 10);
    v[0] = 1.f;
#pragma unroll
    for (int c = 0; c < 10; c++) v[1 + c] = in[c * NPIX + p];
  }
  float4* op = (float4*)(itp + idx * 16);
#pragma unroll
  for (int g = 0; g < 4; g++)
    op[g] = make_float4(v[g * 4], v[g * 4 + 1], v[g * 4 + 2], v[g * 4 + 3]);
}

// ---------------------------------------------------------------------------
// weight repack to MFMA-fragment-major order:
//   wb[L][t][cf][kc][lane][e]  (f16), co = cf*16 + (lane&15),
//   ci = kc*32 + (lane>>4)*8 + e  -> one wave A-frag load = contiguous 1KB.
// ---------------------------------------------------------------------------
__global__ __launch_bounds__(256) void pack_wmid_k(
    const float* __restrict__ wm, f16* __restrict__ wb) {
  int idx = blockIdx.x * 256 + threadIdx.x;  // 23*9*16384
  int e = idx & 7;
  int l = (idx >> 3) & 63;
  int kc = (idx >> 9) & 3;
  int cf = (idx >> 11) & 7;
  int tL = idx >> 14;
  int L = tL / 9;
  int t = tL - L * 9;
  int co = cf * 16 + (l & 15);
  int ci = kc * 32 + (l >> 4) * 8 + e;
  float v = 0.f;
  if (co < 100 && ci < 100) v = wm[((L * 100 + co) * 100 + ci) * 9 + t];
  wb[idx] = (f16)v;
}

// wfin [441][100][3][3] f32 -> [9][32cf][4kc][64][8]  (co padded to 512)
__global__ __launch_bounds__(256) void pack_wfin_k(
    const float* __restrict__ wf, f16* __restrict__ wb) {
  int idx = blockIdx.x * 256 + threadIdx.x;  // 9*65536
  int e = idx & 7;
  int l = (idx >> 3) & 63;
  int kc = (idx >> 9) & 3;
  int cf = (idx >> 11) & 31;
  int t = idx >> 16;
  int co = cf * 16 + (l & 15);
  int ci = kc * 32 + (l >> 4) * 8 + e;
  float v = 0.f;
  if (co < 441 && ci < 100) v = wf[(co * 100 + ci) * 9 + t];
  wb[idx] = (f16)v;
}

// ---------------------------------------------------------------------------
// conv0: 10 -> 100 direct fp32, write f16 halo NHWC [HPIX][128]
// ---------------------------------------------------------------------------
__global__ __launch_bounds__(256) void conv0_k(
    const float* __restrict__ in, const float* __restrict__ w0,
    const float* __restrict__ b0, f16* __restrict__ act) {
  const int tx = threadIdx.x & 15, ty = threadIdx.x >> 4;
  const int x = blockIdx.x * 16 + tx, y = blockIdx.y * 16 + ty;
  const int co0 = blockIdx.z * 16;
  const int nco = max(0, min(16, 100 - co0));
  float acc[16];
#pragma unroll
  for (int i = 0; i < 16; i++) acc[i] = (i < nco) ? b0[co0 + i] : 0.f;
  for (int ci = 0; ci < 10; ci++) {
    const float* ip = in + ci * NPIX;
    float v[9];
#pragma unroll
    for (int t = 0; t < 9; t++) {
      int ny = y + t / 3 - 1, nx = x + t % 3 - 1;
      bool ok = ((unsigned)ny < (unsigned)HW) && ((unsigned)nx < (unsigned)HW);
      v[t] = ok ? ip[ny * HW + nx] : 0.f;
    }
    const float* wp = w0 + (co0 * 10 + ci) * 9;
#pragma unroll
    for (int i = 0; i < 16; i++) {
      if (i < nco) {
#pragma unroll
        for (int t = 0; t < 9; t++)
          acc[i] = fmaf(wp[i * 90 + t], v[t], acc[i]);
      }
    }
  }
  f16* op = act + ((y + 1) * HB + (x + 1)) * 128 + co0;
#pragma unroll
  for (int g = 0; g < 4; g++) {
    f16x4 sv;
#pragma unroll
    for (int j = 0; j < 4; j++) sv[j] = (f16)acc[g * 4 + j];
    *(f16x4*)(op + g * 4) = sv;
  }
}

// ---------------------------------------------------------------------------
// implicit-GEMM 3x3 conv, MFMA f16.
// B (activations) staged once in LDS (XOR chunk swizzle, 50.6 KB).
// A (weights) double-buffered in LDS via global_load_lds (2 x 32 KB),
// prefetched one tap ahead; one barrier per tap.
// Block = 256 thr = 4 waves, tile 128co x 64px. Wave = 64co x 32px, acc[4][2].
// grid = (256 [y*2 + xhalf], co_blocks).  wb: frag-major [9][NCF][4][64][8].
// ---------------------------------------------------------------------------
template <int NCF, bool FINAL>
__global__ __launch_bounds__(256) void conv_mfma_k(
    const f16* __restrict__ act, const f16* __restrict__ wb,
    const float* __restrict__ bias, f16* __restrict__ out) {
  __shared__ f16 ldsB[3 * 66 * 128];   // 50688 B
  __shared__ f16 ldsA[2][2048 * 8];    // 65536 B
  f16x8* ldsB8 = (f16x8*)ldsB;
  const f16x8* actF8 = (const f16x8*)act;

  const int tid = threadIdx.x;
  const int l = tid & 63;
  const int w = tid >> 6;
  const int lr = l & 15;
  const int lg = l >> 4;
  const int y = blockIdx.x >> 1;
  const int x0 = (blockIdx.x & 1) * 64;
  const int co_half = w >> 1;
  const int px_half = w & 1;
  const int cfb = blockIdx.y * 8;      // block's global cf base
  const int chw = co_half * 4;         // wave's local cf base
  const int lpb = px_half * 32 + lr;
  const int wbase = tid & 192;         // wave-uniform lane base (w*64)

  // ---- stage B tile: rows y..y+2 (halo coords), px x0..x0+65, swizzled ----
#pragma unroll
  for (int it = 0; it < 13; it++) {
    int cid = it * 256 + tid;
    if (cid < 3168) {
      int row = cid / 1056;          // 66*16
      int rem = cid - row * 1056;
      int lp = rem >> 4;
      int c = rem & 15;
      f16x8 v = actF8[((y + row) * HB + x0 + lp) * 16 + (c ^ (lp & 7))];
      ldsB8[(row * 66 + lp) * 16 + c] = v;
    }
  }

  // ---- stage A for tap 0 into ldsA[0] (async) ----
#pragma unroll
  for (int j = 0; j < 8; j++) {
    const f16* g = wb + ((long)((0 * NCF + cfb + j) * 256 + tid)) * 8;
    gload16(g, &ldsA[0][(j * 256 + wbase) * 8]);
  }
  __syncthreads();

  f32x4 acc[4][2];
#pragma unroll
  for (int m = 0; m < 4; m++)
#pragma unroll
    for (int n = 0; n < 2; n++) acc[m][n] = f32x4{0.f, 0.f, 0.f, 0.f};

#pragma unroll
  for (int t = 0; t < 9; t++) {
    const int half = t & 1;
    // prefetch next tap's A into the other half (async, drained at barrier)
    if (t < 8) {
#pragma unroll
      for (int j = 0; j < 8; j++) {
        const f16* g = wb + ((long)(((t + 1) * NCF + cfb + j) * 256 + tid)) * 8;
        gload16(g, &ldsA[half ^ 1][(j * 256 + wbase) * 8]);
      }
    }
    // compute tap t
    const int dx = t % 3, r = t / 3;
#pragma unroll
    for (int kc = 0; kc < 4; kc++) {
      f16x8 af[4];
#pragma unroll
      for (int m = 0; m < 4; m++)
        af[m] = *(const f16x8*)&ldsA[half][(((chw + m) * 4 + kc) * 64 + l) * 8];
      const int kq = kc * 4 + lg;
      f16x8 fb[2];
#pragma unroll
      for (int n = 0; n < 2; n++) {
        const int lp = lpb + n * 16 + dx;
        fb[n] = ldsB8[((r * 66 + lp) << 4) + (kq ^ (lp & 7))];
      }
#pragma unroll
      for (int m = 0; m < 4; m++) {
        acc[m][0] = __builtin_amdgcn_mfma_f32_16x16x32_f16(af[m], fb[0], acc[m][0], 0, 0, 0);
        acc[m][1] = __builtin_amdgcn_mfma_f32_16x16x32_f16(af[m], fb[1], acc[m][1], 0, 0, 0);
      }
    }
    __syncthreads();
  }

  // ---- epilogue ----
#pragma unroll
  for (int m = 0; m < 4; m++) {
#pragma unroll
    for (int n = 0; n < 2; n++) {
      int co = blockIdx.y * 128 + co_half * 64 + m * 16 + lg * 4;
      int px = x0 + px_half * 32 + n * 16 + lr;
      if (FINAL && co >= 448) continue;
      f16x4 sv;
#pragma unroll
      for (int j = 0; j < 4; j++) {
        float v;
        if (FINAL) {
          // pad logit channels 441..447 get -inf-ish so softmax ignores them
          v = (co + j < 441) ? acc[m][n][j] + bias[co + j] : -60000.f;
        } else {
          float bv = (co + j < 100) ? bias[co + j] : 0.f;
          v = acc[m][n][j] + bv;
          v = v > 0.f ? v : 0.01f * v;
        }
        sv[j] = (f16)v;
      }
      f16* op = FINAL ? out + (y * HW + px) * 448 + co
                      : out + ((y + 1) * HB + (px + 1)) * 128 + co;
      *(f16x4*)op = sv;
    }
  }
}

// ---------------------------------------------------------------------------
// fused softmax + WLS + solve. 8 threads per pixel (56 taps each, 8-aligned),
// logits held in registers (7 x f16x8), shuffle-reduce over xor 1/2/4.
// inputT: [ITW*ITW][16] f32 halo (ch0=valid). logits: [NPIX][448] f16.
// grid = 512 blocks.
// ---------------------------------------------------------------------------
__global__ __launch_bounds__(256) void wls_k(
    const float* __restrict__ itp, const f16* __restrict__ logits,
    float* __restrict__ out) {
  const int tid = threadIdx.x;
  const int part = tid & 7;
  const int p = blockIdx.x * 32 + (tid >> 3);
  const int x = p & (HW - 1), y = p >> 7;
  const int hpc = (y + 10) * ITW + (x + 10);
  const int k0 = part * 56;

  // load this part's 56 logits once
  const f16x8* lp8 = (const f16x8*)(logits + p * 448 + k0);
  f16x8 lgv[7];
#pragma unroll
  for (int j = 0; j < 7; j++) lgv[j] = lp8[j];

  float m = -1e30f;
#pragma unroll
  for (int j = 0; j < 7; j++)
#pragma unroll
    for (int e = 0; e < 8; e++) m = fmaxf(m, (float)lgv[j][e]);
  m = fmaxf(m, __shfl_xor(m, 1));
  m = fmaxf(m, __shfl_xor(m, 2));
  m = fmaxf(m, __shfl_xor(m, 4));

  float A[36];
#pragma unroll
  for (int i = 0; i < 36; i++) A[i] = 0.f;
  float Bm[24];
#pragma unroll
  for (int i = 0; i < 24; i++) Bm[i] = 0.f;
  float S = 0.f;

#pragma unroll
  for (int j = 0; j < 7; j++) {
#pragma unroll
    for (int e = 0; e < 8; e++) {
      const int k = k0 + j * 8 + e;
      const float u = __expf((float)lgv[j][e] - m);
      S += u;
      if (k < 441) {
        const int ky = k / 21, kx = k - (k / 21) * 21;
        const float4* q =
            (const float4*)(itp + (hpc + (ky - 10) * ITW + (kx - 10)) * 16);
        float4 f0 = q[0], f1 = q[1], f2 = q[2];
        float xv[8] = {f0.x, f1.x, f1.y, f1.z, f1.w, f2.x, f2.y, f2.z};
        float yv[3] = {f0.y, f0.z, f0.w};
        float ux[8];
#pragma unroll
        for (int i = 0; i < 8; i++) ux[i] = u * xv[i];
#pragma unroll
        for (int i = 0; i < 8; i++)
#pragma unroll
          for (int jj = i; jj < 8; jj++) {
            const int idx = i * 8 - i * (i - 1) / 2 + (jj - i);
            A[idx] = fmaf(ux[i], xv[jj], A[idx]);
          }
#pragma unroll
        for (int i = 0; i < 8; i++)
#pragma unroll
          for (int c = 0; c < 3; c++)
            Bm[i * 3 + c] = fmaf(ux[i], yv[c], Bm[i * 3 + c]);
      }
    }
  }

  // cross-part reduction (8 lanes per pixel)
#pragma unroll
  for (int i = 0; i < 36; i++) {
    A[i] += __shfl_xor(A[i], 1);
    A[i] += __shfl_xor(A[i], 2);
    A[i] += __shfl_xor(A[i], 4);
  }
#pragma unroll
  for (int i = 0; i < 24; i++) {
    Bm[i] += __shfl_xor(Bm[i], 1);
    Bm[i] += __shfl_xor(Bm[i], 2);
    Bm[i] += __shfl_xor(Bm[i], 4);
  }
  S += __shfl_xor(S, 1);
  S += __shfl_xor(S, 2);
  S += __shfl_xor(S, 4);

  float M[8][8];
#pragma unroll
  for (int i = 0; i < 8; i++)
#pragma unroll
    for (int j = 0; j < 8; j++) {
      const int lo = (i < j) ? i : j;
      const int hi = (i < j) ? j : i;
      M[i][j] = A[lo * 8 - lo * (lo - 1) / 2 + (hi - lo)];
    }
#pragma unroll
  for (int i = 1; i < 8; i++) M[i][i] += S * EPS;

  float R[8][3];
#pragma unroll
  for (int i = 0; i < 8; i++)
#pragma unroll
    for (int c = 0; c < 3; c++) R[i][c] = Bm[i * 3 + c];

#pragma unroll
  for (int c = 0; c < 8; c++) {
    const float inv = 1.f / M[c][c];
#pragma unroll
    for (int r = c + 1; r < 8; r++) {
      const float f = M[r][c] * inv;
#pragma unroll
      for (int j = c + 1; j < 8; j++) M[r][j] = fmaf(-f, M[c][j], M[r][j]);
#pragma unroll
      for (int cc = 0; cc < 3; cc++) R[r][cc] = fmaf(-f, R[c][cc], R[r][cc]);
    }
  }
  float para[8][3];
#pragma unroll
  for (int r = 7; r >= 0; r--) {
#pragma unroll
    for (int cc = 0; cc < 3; cc++) {
      float s = R[r][cc];
#pragma unroll
      for (int j = r + 1; j < 8; j++) s = fmaf(-M[r][j], para[j][cc], s);
      para[r][cc] = s / M[r][r];
    }
  }

  const float4* qc = (const float4*)(itp + hpc * 16);
  float4 c1 = qc[1], c2 = qc[2];
  float dv[8] = {1.f, c1.x, c1.y, c1.z, c1.w, c2.x, c2.y, c2.z};
  float res = 0.f;
  if (part < 3) {
#pragma unroll
    for (int i = 0; i < 8; i++) res = fmaf(dv[i], para[i][part], res);
    out[part * NPIX + p] = res;
  }
}

// ---------------------------------------------------------------------------
extern "C" void kernel_launch(void* const* d_in, const int* in_sizes, int n_in,
                              void* d_out, int out_size, void* d_ws, size_t ws_size,
                              hipStream_t stream) {
  const float* input = (const float*)d_in[0];
  const float* w0 = (const float*)d_in[2];
  const float* b0 = (const float*)d_in[3];
  const float* wmid = (const float*)d_in[4];
  const float* bmid = (const float*)d_in[5];
  const float* wfin = (const float*)d_in[6];
  const float* bfin = (const float*)d_in[7];
  float* out = (float*)d_out;

  f16* act0 = (f16*)d_ws;                           // HPIX*128
  f16* act1 = act0 + HPIX * 128;                    // HPIX*128
  f16* logits = act1 + HPIX * 128;                  // NPIX*448
  f16* wbuf = logits + NPIX * 448;                  // 23*9*16384
  f16* wfbuf = wbuf + 23 * 9 * 16384;               // 9*65536
  float* inputT = (float*)(wfbuf + 9 * 65536);      // 148*148*16

  // zero both act buffers (halo + pad channels)
  {
    int n = (2 * HPIX * 128 * 2) / 16;
    zero_buf<<<(n + 255) / 256, 256, 0, stream>>>((i32x4*)act0, n);
  }
  prep_input_k<<<(ITW * ITW + 255) / 256, 256, 0, stream>>>(input, inputT);
  pack_wmid_k<<<(23 * 9 * 16384) / 256, 256, 0, stream>>>(wmid, wbuf);
  pack_wfin_k<<<(9 * 65536) / 256, 256, 0, stream>>>(wfin, wfbuf);

  conv0_k<<<dim3(8, 8, 8), 256, 0, stream>>>(input, w0, b0, act0);

  for (int L = 0; L < 23; L++) {
    const f16* src = (L & 1) ? act1 : act0;
    f16* dst = (L & 1) ? act0 : act1;
    conv_mfma_k<8, false><<<dim3(256, 1), 256, 0, stream>>>(
        src, wbuf + (long)L * 9 * 16384, bmid + L * 100, dst);
  }
  // 23 layers end in act1
  conv_mfma_k<32, true><<<dim3(256, 4), 256, 0, stream>>>(
      act1, wfbuf, bfin, logits);

  wls_k<<<NPIX * 8 / 256, 256, 0, stream>>>(inputT, logits, out);
}

// Round 6
// 532.747 us; speedup vs baseline: 5.8787x; 1.0357x over previous
//
#include <hip/hip_runtime.h>
#include <hip/hip_bf16.h>

#define HW 128
#define NPIX (HW * HW)
#define HB 130            // halo-padded activation image width
#define HPIX (HB * HB)
#define ITW 148           // halo-padded transposed-input width (halo 10)
#define EPS 1e-4f

typedef __attribute__((ext_vector_type(4))) float f32x4;
typedef _Float16 f16;
typedef __attribute__((ext_vector_type(8))) _Float16 f16x8;
typedef __attribute__((ext_vector_type(4))) _Float16 f16x4;
typedef __attribute__((ext_vector_type(4))) int i32x4;

// async global->LDS, 16B per lane; l must be wave-uniform base
__device__ __forceinline__ void gload16(const f16* g, f16* l) {
  __builtin_amdgcn_global_load_lds(
      (const __attribute__((address_space(1))) unsigned int*)(const void*)g,
      (__attribute__((address_space(3))) unsigned int*)(void*)l, 16, 0, 0);
}

// ---------------------------------------------------------------------------
__global__ __launch_bounds__(256) void zero_buf(i32x4* __restrict__ p, int n) {
  int i = blockIdx.x * 256 + threadIdx.x;
  if (i < n) p[i] = i32x4{0, 0, 0, 0};
}

// ---------------------------------------------------------------------------
// transpose input NCHW fp32 -> halo-padded [148*148][16] fp32
// ch0 = validity/ones, ch1..3 = input[0..2], ch4..10 = input[3..9], rest 0
// ---------------------------------------------------------------------------
__global__ __launch_bounds__(256) void prep_input_k(
    const float* __restrict__ in, float* __restrict__ itp) {
  int idx = blockIdx.x * 256 + threadIdx.x;
  if (idx >= ITW * ITW) return;
  int py = idx / ITW, px = idx - py * ITW;
  float v[16];
#pragma unroll
  for (int i = 0; i < 16; i++) v[i] = 0.f;
  if (py >= 10 && py < 138 && px >= 10 && px < 138) {
    int p = (py - 10) * HW + (px - 10);
    v[0] = 1.f;
#pragma unroll
    for (int c = 0; c < 10; c++) v[1 + c] = in[c * NPIX + p];
  }
  float4* op = (float4*)(itp + idx * 16);
#pragma unroll
  for (int g = 0; g < 4; g++)
    op[g] = make_float4(v[g * 4], v[g * 4 + 1], v[g * 4 + 2], v[g * 4 + 3]);
}

// ---------------------------------------------------------------------------
// weight repack to MFMA-fragment-major order:
//   wb[L][t][cf][kc][lane][e]  (f16), co = cf*16 + (lane&15),
//   ci = kc*32 + (lane>>4)*8 + e  -> one wave A-frag load = contiguous 1KB.
// ---------------------------------------------------------------------------
__global__ __launch_bounds__(256) void pack_wmid_k(
    const float* __restrict__ wm, f16* __restrict__ wb) {
  int idx = blockIdx.x * 256 + threadIdx.x;  // 23*9*16384
  int e = idx & 7;
  int l = (idx >> 3) & 63;
  int kc = (idx >> 9) & 3;
  int cf = (idx >> 11) & 7;
  int tL = idx >> 14;
  int L = tL / 9;
  int t = tL - L * 9;
  int co = cf * 16 + (l & 15);
  int ci = kc * 32 + (l >> 4) * 8 + e;
  float v = 0.f;
  if (co < 100 && ci < 100) v = wm[((L * 100 + co) * 100 + ci) * 9 + t];
  wb[idx] = (f16)v;
}

// wfin [441][100][3][3] f32 -> [9][32cf][4kc][64][8]  (co padded to 512)
__global__ __launch_bounds__(256) void pack_wfin_k(
    const float* __restrict__ wf, f16* __restrict__ wb) {
  int idx = blockIdx.x * 256 + threadIdx.x;  // 9*65536
  int e = idx & 7;
  int l = (idx >> 3) & 63;
  int kc = (idx >> 9) & 3;
  int cf = (idx >> 11) & 31;
  int t = idx >> 16;
  int co = cf * 16 + (l & 15);
  int ci = kc * 32 + (l >> 4) * 8 + e;
  float v = 0.f;
  if (co < 441 && ci < 100) v = wf[(co * 100 + ci) * 9 + t];
  wb[idx] = (f16)v;
}

// ---------------------------------------------------------------------------
// conv0: 10 -> 100 direct fp32, write f16 halo NHWC [HPIX][128]
// ---------------------------------------------------------------------------
__global__ __launch_bounds__(256) void conv0_k(
    const float* __restrict__ in, const float* __restrict__ w0,
    const float* __restrict__ b0, f16* __restrict__ act) {
  const int tx = threadIdx.x & 15, ty = threadIdx.x >> 4;
  const int x = blockIdx.x * 16 + tx, y = blockIdx.y * 16 + ty;
  const int co0 = blockIdx.z * 16;
  const int nco = max(0, min(16, 100 - co0));
  float acc[16];
#pragma unroll
  for (int i = 0; i < 16; i++) acc[i] = (i < nco) ? b0[co0 + i] : 0.f;
  for (int ci = 0; ci < 10; ci++) {
    const float* ip = in + ci * NPIX;
    float v[9];
#pragma unroll
    for (int t = 0; t < 9; t++) {
      int ny = y + t / 3 - 1, nx = x + t % 3 - 1;
      bool ok = ((unsigned)ny < (unsigned)HW) && ((unsigned)nx < (unsigned)HW);
      v[t] = ok ? ip[ny * HW + nx] : 0.f;
    }
    const float* wp = w0 + (co0 * 10 + ci) * 9;
#pragma unroll
    for (int i = 0; i < 16; i++) {
      if (i < nco) {
#pragma unroll
        for (int t = 0; t < 9; t++)
          acc[i] = fmaf(wp[i * 90 + t], v[t], acc[i]);
      }
    }
  }
  f16* op = act + ((y + 1) * HB + (x + 1)) * 128 + co0;
#pragma unroll
  for (int g = 0; g < 4; g++) {
    f16x4 sv;
#pragma unroll
    for (int j = 0; j < 4; j++) sv[j] = (f16)acc[g * 4 + j];
    *(f16x4*)(op + g * 4) = sv;
  }
}

// ---------------------------------------------------------------------------
// implicit-GEMM 3x3 conv, MFMA f16, software-pipelined taps (T3/T4):
//  - B staged once in LDS (XOR chunk swizzle, 50.6 KB), lgkm-synced once.
//  - A 3-buffer LDS pipeline via global_load_lds, 2 taps in flight,
//    counted s_waitcnt vmcnt(8) + RAW s_barrier (never vmcnt(0) mid-loop).
// Block = 256 thr = 4 waves, tile 128co x 64px. Wave = 64co x 32px, acc[4][2].
// grid = (256 [y*2 + xhalf], co_blocks).  wb: frag-major [9][NCF][4][64][8].
// LDS total: 50688 + 3*32768 = 149 KB -> 1 block/CU (ILP design, not TLP).
// ---------------------------------------------------------------------------
template <int NCF, bool FINAL>
__global__ __launch_bounds__(256) void conv_mfma_k(
    const f16* __restrict__ act, const f16* __restrict__ wb,
    const float* __restrict__ bias, f16* __restrict__ out) {
  __shared__ f16 ldsB[3 * 66 * 128];     // 50688 B
  __shared__ f16 ldsA[3][2048 * 8];      // 3 x 32768 B
  f16x8* ldsB8 = (f16x8*)ldsB;
  const f16x8* actF8 = (const f16x8*)act;

  const int tid = threadIdx.x;
  const int l = tid & 63;
  const int w = tid >> 6;
  const int lr = l & 15;
  const int lg = l >> 4;
  const int y = blockIdx.x >> 1;
  const int x0 = (blockIdx.x & 1) * 64;
  const int co_half = w >> 1;
  const int px_half = w & 1;
  const int cfb = blockIdx.y * 8;      // block's global cf base
  const int chw = co_half * 4;         // wave's local cf base
  const int lpb = px_half * 32 + lr;
  const int wbase = tid & 192;         // wave-uniform lane base (w*64)

  // ---- stage B tile: rows y..y+2 (halo coords), px x0..x0+65, swizzled ----
#pragma unroll
  for (int it = 0; it < 13; it++) {
    int cid = it * 256 + tid;
    if (cid < 3168) {
      int row = cid / 1056;          // 66*16
      int rem = cid - row * 1056;
      int lp = rem >> 4;
      int c = rem & 15;
      f16x8 v = actF8[((y + row) * HB + x0 + lp) * 16 + (c ^ (lp & 7))];
      ldsB8[(row * 66 + lp) * 16 + c] = v;
    }
  }

  // ---- prologue: stage A taps 0,1 into buffers 0,1 (async) ----
#pragma unroll
  for (int j = 0; j < 8; j++) {
    const f16* g = wb + ((long)((0 * NCF + cfb + j) * 256 + tid)) * 8;
    gload16(g, &ldsA[0][(j * 256 + wbase) * 8]);
  }
#pragma unroll
  for (int j = 0; j < 8; j++) {
    const f16* g = wb + ((long)((1 * NCF + cfb + j) * 256 + tid)) * 8;
    gload16(g, &ldsA[1][(j * 256 + wbase) * 8]);
  }
  // B ds_writes must be visible to all waves before any B ds_read
  asm volatile("s_waitcnt lgkmcnt(0)" ::: "memory");
  __builtin_amdgcn_s_barrier();

  f32x4 acc[4][2];
#pragma unroll
  for (int m = 0; m < 4; m++)
#pragma unroll
    for (int n = 0; n < 2; n++) acc[m][n] = f32x4{0.f, 0.f, 0.f, 0.f};

#pragma unroll
  for (int t = 0; t < 9; t++) {
    // wait for tap t's A-stage; keep tap t+1's 8 loads in flight (T4)
    if (t < 8) {
      asm volatile("s_waitcnt vmcnt(8)" ::: "memory");
    } else {
      asm volatile("s_waitcnt vmcnt(0)" ::: "memory");
    }
    __builtin_amdgcn_sched_barrier(0);
    __builtin_amdgcn_s_barrier();
    // issue tap t+2 into buffer (t+2)%3 (its readers finished at iter t-1)
    if (t + 2 <= 8) {
      const int nb = (t + 2) % 3;
#pragma unroll
      for (int j = 0; j < 8; j++) {
        const f16* g = wb + ((long)(((t + 2) * NCF + cfb + j) * 256 + tid)) * 8;
        gload16(g, &ldsA[nb][(j * 256 + wbase) * 8]);
      }
    }
    // compute tap t from buffer t%3
    const int cb = t % 3;
    const int dx = t % 3 == t % 3 ? (t % 3, t - (t / 3) * 3) : 0;  // t%3
    const int r = t / 3;
#pragma unroll
    for (int kc = 0; kc < 4; kc++) {
      f16x8 af[4];
#pragma unroll
      for (int m = 0; m < 4; m++)
        af[m] = *(const f16x8*)&ldsA[cb][(((chw + m) * 4 + kc) * 64 + l) * 8];
      const int kq = kc * 4 + lg;
      f16x8 fb[2];
#pragma unroll
      for (int n = 0; n < 2; n++) {
        const int lp = lpb + n * 16 + dx;
        fb[n] = ldsB8[((r * 66 + lp) << 4) + (kq ^ (lp & 7))];
      }
#pragma unroll
      for (int m = 0; m < 4; m++) {
        acc[m][0] = __builtin_amdgcn_mfma_f32_16x16x32_f16(af[m], fb[0], acc[m][0], 0, 0, 0);
        acc[m][1] = __builtin_amdgcn_mfma_f32_16x16x32_f16(af[m], fb[1], acc[m][1], 0, 0, 0);
      }
    }
  }

  // ---- epilogue ----
#pragma unroll
  for (int m = 0; m < 4; m++) {
#pragma unroll
    for (int n = 0; n < 2; n++) {
      int co = blockIdx.y * 128 + co_half * 64 + m * 16 + lg * 4;
      int px = x0 + px_half * 32 + n * 16 + lr;
      if (FINAL && co >= 448) continue;
      f16x4 sv;
#pragma unroll
      for (int j = 0; j < 4; j++) {
        float v;
        if (FINAL) {
          // pad logit channels 441..447 get -inf-ish so softmax ignores them
          v = (co + j < 441) ? acc[m][n][j] + bias[co + j] : -60000.f;
        } else {
          float bv = (co + j < 100) ? bias[co + j] : 0.f;
          v = acc[m][n][j] + bv;
          v = v > 0.f ? v : 0.01f * v;
        }
        sv[j] = (f16)v;
      }
      f16* op = FINAL ? out + (y * HW + px) * 448 + co
                      : out + ((y + 1) * HB + (px + 1)) * 128 + co;
      *(f16x4*)op = sv;
    }
  }
}

// ---------------------------------------------------------------------------
// fused softmax + WLS + solve. 16 threads per pixel (28 taps each),
// logits in registers (7 x f16x4), shuffle-reduce over xor 1/2/4/8.
// inputT: [ITW*ITW][16] f32 halo (ch0=valid). logits: [NPIX][448] f16
// (channels 441..447 hold -60000 -> exp == 0). grid = 1024 blocks.
// ---------------------------------------------------------------------------
__global__ __launch_bounds__(256) void wls_k(
    const float* __restrict__ itp, const f16* __restrict__ logits,
    float* __restrict__ out) {
  const int tid = threadIdx.x;
  const int part = tid & 15;
  const int p = blockIdx.x * 16 + (tid >> 4);
  const int x = p & (HW - 1), y = p >> 7;
  const int hpc = (y + 10) * ITW + (x + 10);
  const int k0 = part * 28;

  // load this part's 28 logits once (8B-aligned f16x4 loads)
  const f16x4* lp4 = (const f16x4*)(logits + p * 448 + k0);
  f16x4 lgv[7];
#pragma unroll
  for (int j = 0; j < 7; j++) lgv[j] = lp4[j];

  float m = -1e30f;
#pragma unroll
  for (int j = 0; j < 7; j++)
#pragma unroll
    for (int e = 0; e < 4; e++) m = fmaxf(m, (float)lgv[j][e]);
  m = fmaxf(m, __shfl_xor(m, 1));
  m = fmaxf(m, __shfl_xor(m, 2));
  m = fmaxf(m, __shfl_xor(m, 4));
  m = fmaxf(m, __shfl_xor(m, 8));

  float A[36];
#pragma unroll
  for (int i = 0; i < 36; i++) A[i] = 0.f;
  float Bm[24];
#pragma unroll
  for (int i = 0; i < 24; i++) Bm[i] = 0.f;
  float S = 0.f;

#pragma unroll
  for (int j = 0; j < 7; j++) {
#pragma unroll
    for (int e = 0; e < 4; e++) {
      const int k = k0 + j * 4 + e;
      const float u = __expf((float)lgv[j][e] - m);
      S += u;
      if (k < 441) {
        const int ky = k / 21, kx = k - (k / 21) * 21;
        const float4* q =
            (const float4*)(itp + (hpc + (ky - 10) * ITW + (kx - 10)) * 16);
        float4 f0 = q[0], f1 = q[1], f2 = q[2];
        float xv[8] = {f0.x, f1.x, f1.y, f1.z, f1.w, f2.x, f2.y, f2.z};
        float yv[3] = {f0.y, f0.z, f0.w};
        float ux[8];
#pragma unroll
        for (int i = 0; i < 8; i++) ux[i] = u * xv[i];
#pragma unroll
        for (int i = 0; i < 8; i++)
#pragma unroll
          for (int jj = i; jj < 8; jj++) {
            const int idx = i * 8 - i * (i - 1) / 2 + (jj - i);
            A[idx] = fmaf(ux[i], xv[jj], A[idx]);
          }
#pragma unroll
        for (int i = 0; i < 8; i++)
#pragma unroll
          for (int c = 0; c < 3; c++)
            Bm[i * 3 + c] = fmaf(ux[i], yv[c], Bm[i * 3 + c]);
      }
    }
  }

  // cross-part reduction (16 lanes per pixel)
#pragma unroll
  for (int i = 0; i < 36; i++) {
    A[i] += __shfl_xor(A[i], 1);
    A[i] += __shfl_xor(A[i], 2);
    A[i] += __shfl_xor(A[i], 4);
    A[i] += __shfl_xor(A[i], 8);
  }
#pragma unroll
  for (int i = 0; i < 24; i++) {
    Bm[i] += __shfl_xor(Bm[i], 1);
    Bm[i] += __shfl_xor(Bm[i], 2);
    Bm[i] += __shfl_xor(Bm[i], 4);
    Bm[i] += __shfl_xor(Bm[i], 8);
  }
  S += __shfl_xor(S, 1);
  S += __shfl_xor(S, 2);
  S += __shfl_xor(S, 4);
  S += __shfl_xor(S, 8);

  float M[8][8];
#pragma unroll
  for (int i = 0; i < 8; i++)
#pragma unroll
    for (int j = 0; j < 8; j++) {
      const int lo = (i < j) ? i : j;
      const int hi = (i < j) ? j : i;
      M[i][j] = A[lo * 8 - lo * (lo - 1) / 2 + (hi - lo)];
    }
#pragma unroll
  for (int i = 1; i < 8; i++) M[i][i] += S * EPS;

  float R[8][3];
#pragma unroll
  for (int i = 0; i < 8; i++)
#pragma unroll
    for (int c = 0; c < 3; c++) R[i][c] = Bm[i * 3 + c];

#pragma unroll
  for (int c = 0; c < 8; c++) {
    const float inv = 1.f / M[c][c];
#pragma unroll
    for (int r = c + 1; r < 8; r++) {
      const float f = M[r][c] * inv;
#pragma unroll
      for (int j = c + 1; j < 8; j++) M[r][j] = fmaf(-f, M[c][j], M[r][j]);
#pragma unroll
      for (int cc = 0; cc < 3; cc++) R[r][cc] = fmaf(-f, R[c][cc], R[r][cc]);
    }
  }
  float para[8][3];
#pragma unroll
  for (int r = 7; r >= 0; r--) {
#pragma unroll
    for (int cc = 0; cc < 3; cc++) {
      float s = R[r][cc];
#pragma unroll
      for (int j = r + 1; j < 8; j++) s = fmaf(-M[r][j], para[j][cc], s);
      para[r][cc] = s / M[r][r];
    }
  }

  const float4* qc = (const float4*)(itp + hpc * 16);
  float4 c1 = qc[1], c2 = qc[2];
  float dv[8] = {1.f, c1.x, c1.y, c1.z, c1.w, c2.x, c2.y, c2.z};
  float res = 0.f;
  if (part < 3) {
#pragma unroll
    for (int i = 0; i < 8; i++) res = fmaf(dv[i], para[i][part], res);
    out[part * NPIX + p] = res;
  }
}

// ---------------------------------------------------------------------------
extern "C" void kernel_launch(void* const* d_in, const int* in_sizes, int n_in,
                              void* d_out, int out_size, void* d_ws, size_t ws_size,
                              hipStream_t stream) {
  const float* input = (const float*)d_in[0];
  const float* w0 = (const float*)d_in[2];
  const float* b0 = (const float*)d_in[3];
  const float* wmid = (const float*)d_in[4];
  const float* bmid = (const float*)d_in[5];
  const float* wfin = (const float*)d_in[6];
  const float* bfin = (const float*)d_in[7];
  float* out = (float*)d_out;

  f16* act0 = (f16*)d_ws;                           // HPIX*128
  f16* act1 = act0 + HPIX * 128;                    // HPIX*128
  f16* logits = act1 + HPIX * 128;                  // NPIX*448
  f16* wbuf = logits + NPIX * 448;                  // 23*9*16384
  f16* wfbuf = wbuf + 23 * 9 * 16384;               // 9*65536
  float* inputT = (float*)(wfbuf + 9 * 65536);      // 148*148*16

  // zero both act buffers (halo + pad channels)
  {
    int n = (2 * HPIX * 128 * 2) / 16;
    zero_buf<<<(n + 255) / 256, 256, 0, stream>>>((i32x4*)act0, n);
  }
  prep_input_k<<<(ITW * ITW + 255) / 256, 256, 0, stream>>>(input, inputT);
  pack_wmid_k<<<(23 * 9 * 16384) / 256, 256, 0, stream>>>(wmid, wbuf);
  pack_wfin_k<<<(9 * 65536) / 256, 256, 0, stream>>>(wfin, wfbuf);

  conv0_k<<<dim3(8, 8, 8), 256, 0, stream>>>(input, w0, b0, act0);

  for (int L = 0; L < 23; L++) {
    const f16* src = (L & 1) ? act1 : act0;
    f16* dst = (L & 1) ? act0 : act1;
    conv_mfma_k<8, false><<<dim3(256, 1), 256, 0, stream>>>(
        src, wbuf + (long)L * 9 * 16384, bmid + L * 100, dst);
  }
  // 23 layers end in act1
  conv_mfma_k<32, true><<<dim3(256, 4), 256, 0, stream>>>(
      act1, wfbuf, bfin, logits);

  wls_k<<<NPIX * 16 / 256, 256, 0, stream>>>(inputT, logits, out);
}

// Round 7
// 420.206 us; speedup vs baseline: 7.4531x; 1.2678x over previous
//
#include <hip/hip_runtime.h>
#include <hip/hip_bf16.h>

#define HW 128
#define NPIX (HW * HW)
#define HB 130            // halo-padded activation image width
#define HPIX (HB * HB)
#define ITW 148           // halo-padded transposed-input width (halo 10)
#define EPS 1e-4f

typedef __attribute__((ext_vector_type(4))) float f32x4;
typedef _Float16 f16;
typedef __attribute__((ext_vector_type(8))) _Float16 f16x8;
typedef __attribute__((ext_vector_type(4))) _Float16 f16x4;
typedef __attribute__((ext_vector_type(4))) int i32x4;

// async global->LDS, 16B per lane; l must be wave-uniform base
__device__ __forceinline__ void gload16(const f16* g, f16* l) {
  __builtin_amdgcn_global_load_lds(
      (const __attribute__((address_space(1))) unsigned int*)(const void*)g,
      (__attribute__((address_space(3))) unsigned int*)(void*)l, 16, 0, 0);
}

// ---------------------------------------------------------------------------
__global__ __launch_bounds__(256) void zero_buf(i32x4* __restrict__ p, int n) {
  int i = blockIdx.x * 256 + threadIdx.x;
  if (i < n) p[i] = i32x4{0, 0, 0, 0};
}

// ---------------------------------------------------------------------------
// transpose input NCHW fp32 -> halo-padded [148*148][16] fp32
// ch0 = validity/ones, ch1..3 = input[0..2], ch4..10 = input[3..9], rest 0
// ---------------------------------------------------------------------------
__global__ __launch_bounds__(256) void prep_input_k(
    const float* __restrict__ in, float* __restrict__ itp) {
  int idx = blockIdx.x * 256 + threadIdx.x;
  if (idx >= ITW * ITW) return;
  int py = idx / ITW, px = idx - py * ITW;
  float v[16];
#pragma unroll
  for (int i = 0; i < 16; i++) v[i] = 0.f;
  if (py >= 10 && py < 138 && px >= 10 && px < 138) {
    int p = (py - 10) * HW + (px - 10);
    v[0] = 1.f;
#pragma unroll
    for (int c = 0; c < 10; c++) v[1 + c] = in[c * NPIX + p];
  }
  float4* op = (float4*)(itp + idx * 16);
#pragma unroll
  for (int g = 0; g < 4; g++)
    op[g] = make_float4(v[g * 4], v[g * 4 + 1], v[g * 4 + 2], v[g * 4 + 3]);
}

// ---------------------------------------------------------------------------
// weight repack to MFMA-fragment-major order:
//   wb[L][t][cf][kc][lane][e]  (f16), co = cf*16 + (lane&15),
//   ci = kc*32 + (lane>>4)*8 + e  -> one wave A-frag load = contiguous 1KB.
// ---------------------------------------------------------------------------
__global__ __launch_bounds__(256) void pack_wmid_k(
    const float* __restrict__ wm, f16* __restrict__ wb) {
  int idx = blockIdx.x * 256 + threadIdx.x;  // 23*9*16384
  int e = idx & 7;
  int l = (idx >> 3) & 63;
  int kc = (idx >> 9) & 3;
  int cf = (idx >> 11) & 7;
  int tL = idx >> 14;
  int L = tL / 9;
  int t = tL - L * 9;
  int co = cf * 16 + (l & 15);
  int ci = kc * 32 + (l >> 4) * 8 + e;
  float v = 0.f;
  if (co < 100 && ci < 100) v = wm[((L * 100 + co) * 100 + ci) * 9 + t];
  wb[idx] = (f16)v;
}

// wfin [441][100][3][3] f32 -> [9][32cf][4kc][64][8]  (co padded to 512)
__global__ __launch_bounds__(256) void pack_wfin_k(
    const float* __restrict__ wf, f16* __restrict__ wb) {
  int idx = blockIdx.x * 256 + threadIdx.x;  // 9*65536
  int e = idx & 7;
  int l = (idx >> 3) & 63;
  int kc = (idx >> 9) & 3;
  int cf = (idx >> 11) & 31;
  int t = idx >> 16;
  int co = cf * 16 + (l & 15);
  int ci = kc * 32 + (l >> 4) * 8 + e;
  float v = 0.f;
  if (co < 441 && ci < 100) v = wf[(co * 100 + ci) * 9 + t];
  wb[idx] = (f16)v;
}

// ---------------------------------------------------------------------------
// conv0: 10 -> 100 direct fp32, write f16 halo NHWC [HPIX][128]
// ---------------------------------------------------------------------------
__global__ __launch_bounds__(256) void conv0_k(
    const float* __restrict__ in, const float* __restrict__ w0,
    const float* __restrict__ b0, f16* __restrict__ act) {
  const int tx = threadIdx.x & 15, ty = threadIdx.x >> 4;
  const int x = blockIdx.x * 16 + tx, y = blockIdx.y * 16 + ty;
  const int co0 = blockIdx.z * 16;
  const int nco = max(0, min(16, 100 - co0));
  float acc[16];
#pragma unroll
  for (int i = 0; i < 16; i++) acc[i] = (i < nco) ? b0[co0 + i] : 0.f;
  for (int ci = 0; ci < 10; ci++) {
    const float* ip = in + ci * NPIX;
    float v[9];
#pragma unroll
    for (int t = 0; t < 9; t++) {
      int ny = y + t / 3 - 1, nx = x + t % 3 - 1;
      bool ok = ((unsigned)ny < (unsigned)HW) && ((unsigned)nx < (unsigned)HW);
      v[t] = ok ? ip[ny * HW + nx] : 0.f;
    }
    const float* wp = w0 + (co0 * 10 + ci) * 9;
#pragma unroll
    for (int i = 0; i < 16; i++) {
      if (i < nco) {
#pragma unroll
        for (int t = 0; t < 9; t++)
          acc[i] = fmaf(wp[i * 90 + t], v[t], acc[i]);
      }
    }
  }
  f16* op = act + ((y + 1) * HB + (x + 1)) * 128 + co0;
#pragma unroll
  for (int g = 0; g < 4; g++) {
    f16x4 sv;
#pragma unroll
    for (int j = 0; j < 4; j++) sv[j] = (f16)acc[g * 4 + j];
    *(f16x4*)(op + g * 4) = sv;
  }
}

// ---------------------------------------------------------------------------
// implicit-GEMM 3x3 conv, MFMA f16, TLP design:
//  - Block = 4 waves, tile 128co x 32px. Wave = 32co(2cf) x 32px, acc[2][2].
//  - B in LDS [3][34][16ch] (26.1 KB, XOR swizzle), staged once, ONE barrier.
//  - A single-buffer 32 KB, WAVE-PRIVATE 8 KB quarters staged via
//    global_load_lds one tap ahead; per-wave vmcnt/lgkm fences, NO barriers
//    in the tap loop. LDS total 58.9 KB -> 2 blocks/CU (latency hidden by TLP).
// grid = (512 [y*4 + xq], co_blocks). wb: frag-major [9][NCF][4][64][8].
// ---------------------------------------------------------------------------
template <int NCF, bool FINAL>
__global__ __launch_bounds__(256) void conv_mfma_k(
    const f16* __restrict__ act, const f16* __restrict__ wb,
    const float* __restrict__ bias, f16* __restrict__ out) {
  __shared__ f16 ldsB[3 * 34 * 128];   // 26112 B
  __shared__ f16 ldsA[8 * 4 * 64 * 8]; // 32768 B, wave w owns [w*4096, +4096)
  f16x8* ldsB8 = (f16x8*)ldsB;
  const f16x8* actF8 = (const f16x8*)act;

  const int tid = threadIdx.x;
  const int l = tid & 63;
  const int w = tid >> 6;
  const int lr = l & 15;
  const int lg = l >> 4;
  const int y = blockIdx.x >> 2;
  const int x0 = (blockIdx.x & 3) * 32;
  const int cf0 = blockIdx.y * 8;       // block cf base
  const int wslot = w * 4096;           // wave's LDS A region (elems)

  // ---- stage B tile: act rows y..y+2, act cols x0..x0+33, swizzled ----
#pragma unroll
  for (int it = 0; it < 7; it++) {
    int cid = it * 256 + tid;
    if (cid < 1632) {
      int row = cid / 544;             // 34*16
      int rem = cid - row * 544;
      int lp = rem >> 4;
      int c = rem & 15;
      f16x8 v = actF8[((y + row) * HB + x0 + lp) * 16 + (c ^ (lp & 7))];
      ldsB8[(row * 34 + lp) * 16 + c] = v;
    }
  }

  // ---- stage A(0): wave-private cf pair {cf0+2w, cf0+2w+1} (8 KB) ----
#pragma unroll
  for (int j = 0; j < 8; j++)
    gload16(wb + (long)(0 * NCF + cf0 + 2 * w) * 2048 + j * 512 + l * 8,
            &ldsA[wslot + j * 512]);

  // B ds_writes visible to all waves (the only block barrier)
  asm volatile("s_waitcnt lgkmcnt(0)" ::: "memory");
  __builtin_amdgcn_s_barrier();

  f32x4 acc[2][2];
#pragma unroll
  for (int m = 0; m < 2; m++)
#pragma unroll
    for (int n = 0; n < 2; n++) acc[m][n] = f32x4{0.f, 0.f, 0.f, 0.f};

#pragma unroll
  for (int t = 0; t < 9; t++) {
    // wait for this wave's A(t) DMA (issued one tap ago)
    asm volatile("s_waitcnt vmcnt(0)" ::: "memory");
    __builtin_amdgcn_sched_barrier(0);
    // pull A(t) fragments into registers
    f16x8 af[2][4];
#pragma unroll
    for (int m = 0; m < 2; m++)
#pragma unroll
      for (int kc = 0; kc < 4; kc++)
        af[m][kc] =
            *(const f16x8*)&ldsA[wslot + ((m * 4 + kc) * 64 + l) * 8];
    // make sure the reads completed before DMA may overwrite the buffer
    asm volatile("s_waitcnt lgkmcnt(0)" ::: "memory");
    __builtin_amdgcn_sched_barrier(0);
    if (t < 8) {
#pragma unroll
      for (int j = 0; j < 8; j++)
        gload16(wb + (long)((t + 1) * NCF + cf0 + 2 * w) * 2048 + j * 512 + l * 8,
                &ldsA[wslot + j * 512]);
    }
    // compute tap t
    const int dx = t % 3, r = t / 3;
#pragma unroll
    for (int kc = 0; kc < 4; kc++) {
      const int kq = kc * 4 + lg;
      f16x8 fb[2];
#pragma unroll
      for (int n = 0; n < 2; n++) {
        const int lp = lr + n * 16 + dx;
        fb[n] = ldsB8[(r * 34 + lp) * 16 + (kq ^ (lp & 7))];
      }
#pragma unroll
      for (int m = 0; m < 2; m++) {
        acc[m][0] = __builtin_amdgcn_mfma_f32_16x16x32_f16(af[m][kc], fb[0], acc[m][0], 0, 0, 0);
        acc[m][1] = __builtin_amdgcn_mfma_f32_16x16x32_f16(af[m][kc], fb[1], acc[m][1], 0, 0, 0);
      }
    }
  }

  // ---- epilogue ----
#pragma unroll
  for (int m = 0; m < 2; m++) {
#pragma unroll
    for (int n = 0; n < 2; n++) {
      int co = (cf0 + 2 * w + m) * 16 + lg * 4;
      int px = x0 + n * 16 + lr;
      if (FINAL && co >= 448) continue;
      f16x4 sv;
#pragma unroll
      for (int j = 0; j < 4; j++) {
        float v;
        if (FINAL) {
          v = (co + j < 441) ? acc[m][n][j] + bias[co + j] : -60000.f;
        } else {
          float bv = (co + j < 100) ? bias[co + j] : 0.f;
          v = acc[m][n][j] + bv;
          v = v > 0.f ? v : 0.01f * v;
        }
        sv[j] = (f16)v;
      }
      f16* op = FINAL ? out + (y * HW + px) * 448 + co
                      : out + ((y + 1) * HB + (px + 1)) * 128 + co;
      *(f16x4*)op = sv;
    }
  }
}

// ---------------------------------------------------------------------------
// fused softmax + WLS + solve. 16 threads/pixel, INTERLEAVED taps
// (k = part + 16*j) so the 16 part-lanes of a pixel read consecutive window
// columns (coalesced itp reads). In-place packed symmetric GE keeps VGPR low.
// itp: [ITW*ITW][16] f32 halo. logits: [NPIX][448] f16 (441..447 = -60000).
// grid = 1024 blocks.
// ---------------------------------------------------------------------------
#define IDX(i, j) ((i)*8 - (i) * ((i)-1) / 2 + ((j) - (i)))

__global__ __launch_bounds__(256) void wls_k(
    const float* __restrict__ itp, const f16* __restrict__ logits,
    float* __restrict__ out) {
  const int tid = threadIdx.x;
  const int part = tid & 15;
  const int p = blockIdx.x * 16 + (tid >> 4);
  const int x = p & (HW - 1), y = p >> 7;
  const int hpc = (y + 10) * ITW + (x + 10);

  // preload 28 logits: k = part + 16*j
  const f16* lp = logits + p * 448 + part;
  f16 lgv[28];
#pragma unroll
  for (int j = 0; j < 28; j++) lgv[j] = lp[j * 16];

  float m = -1e30f;
#pragma unroll
  for (int j = 0; j < 28; j++) m = fmaxf(m, (float)lgv[j]);
  m = fmaxf(m, __shfl_xor(m, 1));
  m = fmaxf(m, __shfl_xor(m, 2));
  m = fmaxf(m, __shfl_xor(m, 4));
  m = fmaxf(m, __shfl_xor(m, 8));

  float A[36];
#pragma unroll
  for (int i = 0; i < 36; i++) A[i] = 0.f;
  float Bm[24];
#pragma unroll
  for (int i = 0; i < 24; i++) Bm[i] = 0.f;
  float S = 0.f;

  int ky = 0, kx = part;  // k = part + 16*j = 21*ky + kx
#pragma unroll
  for (int j = 0; j < 28; j++) {
    const int k = part + 16 * j;
    const float u = __expf((float)lgv[j] - m);
    S += u;
    if (k < 441) {
      const float4* q =
          (const float4*)(itp + (hpc + (ky - 10) * ITW + (kx - 10)) * 16);
      float4 f0 = q[0], f1 = q[1], f2 = q[2];
      float xv[8] = {f0.x, f1.x, f1.y, f1.z, f1.w, f2.x, f2.y, f2.z};
      float yv[3] = {f0.y, f0.z, f0.w};
      float ux[8];
#pragma unroll
      for (int i = 0; i < 8; i++) ux[i] = u * xv[i];
#pragma unroll
      for (int i = 0; i < 8; i++)
#pragma unroll
        for (int jj = i; jj < 8; jj++)
          A[IDX(i, jj)] = fmaf(ux[i], xv[jj], A[IDX(i, jj)]);
#pragma unroll
      for (int i = 0; i < 8; i++)
#pragma unroll
        for (int c = 0; c < 3; c++)
          Bm[i * 3 + c] = fmaf(ux[i], yv[c], Bm[i * 3 + c]);
    }
    // advance k by 16 in (ky,kx) coords
    kx += 16;
    if (kx >= 21) { kx -= 21; ky += 1; }
  }

  // cross-part reduction (16 lanes per pixel)
#pragma unroll
  for (int i = 0; i < 36; i++) {
    A[i] += __shfl_xor(A[i], 1);
    A[i] += __shfl_xor(A[i], 2);
    A[i] += __shfl_xor(A[i], 4);
    A[i] += __shfl_xor(A[i], 8);
  }
#pragma unroll
  for (int i = 0; i < 24; i++) {
    Bm[i] += __shfl_xor(Bm[i], 1);
    Bm[i] += __shfl_xor(Bm[i], 2);
    Bm[i] += __shfl_xor(Bm[i], 4);
    Bm[i] += __shfl_xor(Bm[i], 8);
  }
  S += __shfl_xor(S, 1);
  S += __shfl_xor(S, 2);
  S += __shfl_xor(S, 4);
  S += __shfl_xor(S, 8);

  // regularization (diagonal, except [0][0])
#pragma unroll
  for (int i = 1; i < 8; i++) A[IDX(i, i)] += S * EPS;

  // in-place packed symmetric Gaussian elimination (SPD, no pivot)
#pragma unroll
  for (int c = 0; c < 8; c++) {
    const float inv = 1.f / A[IDX(c, c)];
#pragma unroll
    for (int r = c + 1; r < 8; r++) {
      const float f = A[IDX(c, r)] * inv;
#pragma unroll
      for (int jj = r; jj < 8; jj++)
        A[IDX(r, jj)] = fmaf(-f, A[IDX(c, jj)], A[IDX(r, jj)]);
#pragma unroll
      for (int cc = 0; cc < 3; cc++)
        Bm[r * 3 + cc] = fmaf(-f, Bm[c * 3 + cc], Bm[r * 3 + cc]);
    }
  }
  // back substitution in place (Bm becomes para)
#pragma unroll
  for (int r = 7; r >= 0; r--) {
#pragma unroll
    for (int cc = 0; cc < 3; cc++) {
      float s = Bm[r * 3 + cc];
#pragma unroll
      for (int jj = r + 1; jj < 8; jj++)
        s = fmaf(-A[IDX(r, jj)], Bm[jj * 3 + cc], s);
      Bm[r * 3 + cc] = s / A[IDX(r, r)];
    }
  }

  const float4* qc = (const float4*)(itp + hpc * 16);
  float4 c1 = qc[1], c2 = qc[2];
  float dv[8] = {1.f, c1.x, c1.y, c1.z, c1.w, c2.x, c2.y, c2.z};
  if (part < 3) {
    float res = 0.f;
#pragma unroll
    for (int i = 0; i < 8; i++) res = fmaf(dv[i], Bm[i * 3 + part], res);
    out[part * NPIX + p] = res;
  }
}

// ---------------------------------------------------------------------------
extern "C" void kernel_launch(void* const* d_in, const int* in_sizes, int n_in,
                              void* d_out, int out_size, void* d_ws, size_t ws_size,
                              hipStream_t stream) {
  const float* input = (const float*)d_in[0];
  const float* w0 = (const float*)d_in[2];
  const float* b0 = (const float*)d_in[3];
  const float* wmid = (const float*)d_in[4];
  const float* bmid = (const float*)d_in[5];
  const float* wfin = (const float*)d_in[6];
  const float* bfin = (const float*)d_in[7];
  float* out = (float*)d_out;

  f16* act0 = (f16*)d_ws;                           // HPIX*128
  f16* act1 = act0 + HPIX * 128;                    // HPIX*128
  f16* logits = act1 + HPIX * 128;                  // NPIX*448
  f16* wbuf = logits + NPIX * 448;                  // 23*9*16384
  f16* wfbuf = wbuf + 23 * 9 * 16384;               // 9*65536
  float* inputT = (float*)(wfbuf + 9 * 65536);      // 148*148*16

  // zero both act buffers (halo + pad channels)
  {
    int n = (2 * HPIX * 128 * 2) / 16;
    zero_buf<<<(n + 255) / 256, 256, 0, stream>>>((i32x4*)act0, n);
  }
  prep_input_k<<<(ITW * ITW + 255) / 256, 256, 0, stream>>>(input, inputT);
  pack_wmid_k<<<(23 * 9 * 16384) / 256, 256, 0, stream>>>(wmid, wbuf);
  pack_wfin_k<<<(9 * 65536) / 256, 256, 0, stream>>>(wfin, wfbuf);

  conv0_k<<<dim3(8, 8, 8), 256, 0, stream>>>(input, w0, b0, act0);

  for (int L = 0; L < 23; L++) {
    const f16* src = (L & 1) ? act1 : act0;
    f16* dst = (L & 1) ? act0 : act1;
    conv_mfma_k<8, false><<<dim3(512, 1), 256, 0, stream>>>(
        src, wbuf + (long)L * 9 * 16384, bmid + L * 100, dst);
  }
  // 23 layers end in act1
  conv_mfma_k<32, true><<<dim3(512, 4), 256, 0, stream>>>(
      act1, wfbuf, bfin, logits);

  wls_k<<<NPIX * 16 / 256, 256, 0, stream>>>(inputT, logits, out);
}